// Round 1
// baseline (1126.016 us; speedup 1.0000x reference)
//
#include <hip/hip_runtime.h>

#define NN 100000
#define NE 1200000
#define NG 256
#define INC 7
#define HID 64
#define OUTC 10

// ---------------- degree / normalization ----------------

__global__ void k_init_deg(float* __restrict__ deg) {
    int i = blockIdx.x * blockDim.x + threadIdx.x;
    if (i < NN) deg[i] = 1.0f;  // self-loop included
}

__global__ void k_deg(const int* __restrict__ dst, float* __restrict__ deg) {
    int e = blockIdx.x * blockDim.x + threadIdx.x;
    if (e < NE) atomicAdd(&deg[dst[e]], 1.0f);
}

__global__ void k_dis(float* __restrict__ deg) {  // in-place: deg -> rsqrt(deg)
    int i = blockIdx.x * blockDim.x + threadIdx.x;
    if (i < NN) deg[i] = rsqrtf(deg[i]);
}

// ---------------- dense h @ W ----------------

// K = 7 (input layer). 4 nodes per 256-thread block.
__global__ void k_gemm_in(const float* __restrict__ x, const float* __restrict__ W,
                          float* __restrict__ out) {
    __shared__ float sW[INC * HID];
    __shared__ float sx[4][INC];
    int tid = threadIdx.x;
    for (int i = tid; i < INC * HID; i += 256) sW[i] = W[i];
    int node0 = blockIdx.x * 4;
    if (tid < 4 * INC) {
        int n = node0 + tid / INC;
        sx[tid / INC][tid % INC] = (n < NN) ? x[n * INC + tid % INC] : 0.0f;
    }
    __syncthreads();
    int n = node0 + (tid >> 6);
    int c = tid & 63;
    if (n < NN) {
        float acc = 0.0f;
#pragma unroll
        for (int k = 0; k < INC; ++k) acc += sx[tid >> 6][k] * sW[k * HID + c];
        out[n * HID + c] = acc;
    }
}

// K = 64 (hidden layers). 4 nodes per 256-thread block; W staged in LDS (16 KB).
__global__ void k_gemm_hid(const float* __restrict__ h, const float* __restrict__ W,
                           float* __restrict__ out) {
    __shared__ float sW[HID * HID];
    __shared__ float sh[4][HID];
    int tid = threadIdx.x;
    for (int i = tid; i < HID * HID; i += 256) sW[i] = W[i];
    int node0 = blockIdx.x * 4;
    {
        int n = node0 + (tid >> 6);
        sh[tid >> 6][tid & 63] = (n < NN) ? h[n * HID + (tid & 63)] : 0.0f;
    }
    __syncthreads();
    int n = node0 + (tid >> 6);
    if (n < NN) {
        int c = tid & 63;
        float acc = 0.0f;
#pragma unroll
        for (int k = 0; k < HID; ++k) acc += sh[tid >> 6][k] * sW[k * HID + c];
        out[n * HID + c] = acc;
    }
}

// ---------------- per-layer elementwise ----------------

// agg = dis^2 * hw + b   (self-loop term + bias; also zero-initializes agg)
__global__ void k_agg_init(const float* __restrict__ hw, const float* __restrict__ dis,
                           const float* __restrict__ b, float* __restrict__ agg) {
    int i = blockIdx.x * blockDim.x + threadIdx.x;
    if (i < NN * HID) {
        int n = i >> 6, c = i & 63;
        float d = dis[n];
        agg[i] = d * d * hw[i] + b[c];
    }
}

// agg[dst] += dis[src]*dis[dst] * hw[src]; one wave (64 lanes = 64 ch) per edge
__global__ void k_scatter(const int* __restrict__ src, const int* __restrict__ dst,
                          const float* __restrict__ dis, const float* __restrict__ hw,
                          float* __restrict__ agg) {
    int t = blockIdx.x * blockDim.x + threadIdx.x;
    int e = t >> 6;
    int c = t & 63;
    if (e < NE) {
        int s = src[e], d = dst[e];
        float norm = dis[s] * dis[d];
        atomicAdd(&agg[d * HID + c], norm * hw[s * HID + c]);
    }
}

__global__ void k_relu(float* __restrict__ h) {
    int i = blockIdx.x * blockDim.x + threadIdx.x;
    if (i < NN * HID) h[i] = fmaxf(h[i], 0.0f);
}

// ---------------- pooling + head ----------------

__global__ void k_pool_init(float* __restrict__ sums, float* __restrict__ cnt) {
    int i = blockIdx.x * blockDim.x + threadIdx.x;
    if (i < NG * HID) sums[i] = 0.0f;
    if (i < NG) cnt[i] = 0.0f;
}

#define PNODES 32
// batch is sorted: accumulate runs of equal graph-id in registers, flush on change.
__global__ void k_pool(const float* __restrict__ h, const int* __restrict__ batch,
                       float* __restrict__ sums, float* __restrict__ cnt) {
    int c = threadIdx.x;  // 64 threads = 64 channels
    int n0 = blockIdx.x * PNODES;
    float acc = 0.0f, fc = 0.0f;
    int curg = -1;
    int nend = n0 + PNODES;
    if (nend > NN) nend = NN;
    for (int n = n0; n < nend; ++n) {
        int g = batch[n];
        if (g != curg) {
            if (curg >= 0) {
                atomicAdd(&sums[curg * HID + c], acc);
                if (c == 0) atomicAdd(&cnt[curg], fc);
            }
            acc = 0.0f; fc = 0.0f; curg = g;
        }
        acc += h[n * HID + c];
        fc += 1.0f;
    }
    if (curg >= 0) {
        atomicAdd(&sums[curg * HID + c], acc);
        if (c == 0) atomicAdd(&cnt[curg], fc);
    }
}

__global__ void k_final(const float* __restrict__ sums, const float* __restrict__ cnt,
                        const float* __restrict__ linW, const float* __restrict__ linb,
                        float* __restrict__ out) {
    int t = blockIdx.x * blockDim.x + threadIdx.x;  // NG*OUTC = 2560
    if (t < NG * OUTC) {
        int g = t / OUTC, o = t % OUTC;
        float cmax = fmaxf(cnt[g], 1.0f);
        float acc = linb[o];
#pragma unroll
        for (int k = 0; k < HID; ++k)
            acc += (sums[g * HID + k] / cmax) * linW[k * OUTC + o];
        out[t] = acc;
    }
}

// ---------------- launch ----------------

extern "C" void kernel_launch(void* const* d_in, const int* in_sizes, int n_in,
                              void* d_out, int out_size, void* d_ws, size_t ws_size,
                              hipStream_t stream) {
    const float* x    = (const float*)d_in[0];
    const int*   ei   = (const int*)d_in[1];   // [2, NE]
    const int*   src  = ei;
    const int*   dst  = ei + NE;
    const int*   batch = (const int*)d_in[2];
    const float* W0 = (const float*)d_in[3];
    const float* b0 = (const float*)d_in[4];
    const float* W1 = (const float*)d_in[5];
    const float* b1 = (const float*)d_in[6];
    const float* W2 = (const float*)d_in[7];
    const float* b2 = (const float*)d_in[8];
    const float* linW = (const float*)d_in[9];
    const float* linb = (const float*)d_in[10];
    float* out = (float*)d_out;

    float* ws = (float*)d_ws;
    float* bufA = ws;                       // [NN*HID]  hw
    float* bufB = bufA + (size_t)NN * HID;  // [NN*HID]  agg / h
    float* dis  = bufB + (size_t)NN * HID;  // [NN]
    float* sums = dis + NN;                 // [NG*HID]
    float* cnt  = sums + NG * HID;          // [NG]

    const int TB = 256;
    int gN   = (NN + TB - 1) / TB;
    int gE   = (NE + TB - 1) / TB;
    int gNH  = (NN * HID + TB - 1) / TB;     // 25000
    int gSC  = (NE * HID + TB - 1) / TB;     // 300000
    int gG   = NN / 4;                       // 25000 (4 nodes/block)

    // normalization
    k_init_deg<<<gN, TB, 0, stream>>>(dis);
    k_deg<<<gE, TB, 0, stream>>>(dst, dis);
    k_dis<<<gN, TB, 0, stream>>>(dis);

    // layer 0: x -> bufB
    k_gemm_in<<<gG, TB, 0, stream>>>(x, W0, bufA);
    k_agg_init<<<gNH, TB, 0, stream>>>(bufA, dis, b0, bufB);
    k_scatter<<<gSC, TB, 0, stream>>>(src, dst, dis, bufA, bufB);
    k_relu<<<gNH, TB, 0, stream>>>(bufB);

    // layer 1: bufB -> bufB
    k_gemm_hid<<<gG, TB, 0, stream>>>(bufB, W1, bufA);
    k_agg_init<<<gNH, TB, 0, stream>>>(bufA, dis, b1, bufB);
    k_scatter<<<gSC, TB, 0, stream>>>(src, dst, dis, bufA, bufB);
    k_relu<<<gNH, TB, 0, stream>>>(bufB);

    // layer 2: bufB -> bufB (no relu)
    k_gemm_hid<<<gG, TB, 0, stream>>>(bufB, W2, bufA);
    k_agg_init<<<gNH, TB, 0, stream>>>(bufA, dis, b2, bufB);
    k_scatter<<<gSC, TB, 0, stream>>>(src, dst, dis, bufA, bufB);

    // pool + head
    k_pool_init<<<(NG * HID + TB - 1) / TB, TB, 0, stream>>>(sums, cnt);
    k_pool<<<NN / PNODES, HID, 0, stream>>>(bufB, batch, sums, cnt);
    k_final<<<(NG * OUTC + TB - 1) / TB, TB, 0, stream>>>(sums, cnt, linW, linb, out);
}

// Round 2
// 728.082 us; speedup vs baseline: 1.5466x; 1.5466x over previous
//
#include <hip/hip_runtime.h>

#define NN 100000
#define NE 1200000
#define NG 256
#define INC 7
#define HID 64
#define OUTC 10
#define NB_SCAN 98   // ceil(NN/1024)

// ---------------- zero init (ws is poisoned 0xAA before every call) ----------------

__global__ void k_zero(int* __restrict__ cnts, float* __restrict__ sums,
                       float* __restrict__ cnt) {
    int i = blockIdx.x * blockDim.x + threadIdx.x;
    if (i < NN) cnts[i] = 0;
    if (i < NG * HID) sums[i] = 0.0f;
    if (i < NG) cnt[i] = 0.0f;
}

// ---------------- degree histogram + normalization ----------------

__global__ void k_count(const int* __restrict__ dst, int* __restrict__ cnts) {
    int e = blockIdx.x * blockDim.x + threadIdx.x;
    if (e < NE) atomicAdd(&cnts[dst[e]], 1);
}

__global__ void k_dis(const int* __restrict__ cnts, float* __restrict__ dis) {
    int i = blockIdx.x * blockDim.x + threadIdx.x;
    if (i < NN) dis[i] = rsqrtf((float)cnts[i] + 1.0f);  // +1 = self-loop
}

// ---------------- exclusive scan (3-pass) ----------------

__global__ __launch_bounds__(1024) void k_scan1(const int* __restrict__ cnts,
                                                int* __restrict__ rowptr,
                                                int* __restrict__ blocksums) {
    __shared__ int tmp[1024];
    int tid = threadIdx.x;
    int i = blockIdx.x * 1024 + tid;
    int v = (i < NN) ? cnts[i] : 0;
    tmp[tid] = v;
    __syncthreads();
    for (int off = 1; off < 1024; off <<= 1) {
        int add = (tid >= off) ? tmp[tid - off] : 0;
        __syncthreads();
        tmp[tid] += add;
        __syncthreads();
    }
    if (i < NN) rowptr[i] = tmp[tid] - v;  // exclusive
    if (tid == 1023) blocksums[blockIdx.x] = tmp[1023];
}

__global__ void k_scan2(int* __restrict__ bs) {  // tiny serial scan of 98 block sums
    if (threadIdx.x == 0 && blockIdx.x == 0) {
        int acc = 0;
        for (int i = 0; i < NB_SCAN; ++i) { int t = bs[i]; bs[i] = acc; acc += t; }
    }
}

__global__ void k_scan3(int* __restrict__ rowptr, const int* __restrict__ bs,
                        int* __restrict__ cursor) {
    int i = blockIdx.x * blockDim.x + threadIdx.x;
    if (i < NN) {
        int r = rowptr[i] + bs[i >> 10];
        rowptr[i] = r;
        cursor[i] = r;
    }
}

// ---------------- CSR fill ----------------

__global__ void k_fill(const int* __restrict__ src, const int* __restrict__ dst,
                       int* __restrict__ cursor, int* __restrict__ csr) {
    int e = blockIdx.x * blockDim.x + threadIdx.x;
    if (e < NE) {
        int p = atomicAdd(&cursor[dst[e]], 1);
        csr[p] = src[e];
    }
}

// ---------------- dense h @ W (epilogue: * dis[n]) ----------------

// K = 7 (input layer). 4 nodes per 256-thread block.
__global__ void k_gemm_in(const float* __restrict__ x, const float* __restrict__ W,
                          const float* __restrict__ dis, float* __restrict__ out) {
    __shared__ float sW[INC * HID];
    __shared__ float sx[4][INC];
    int tid = threadIdx.x;
    for (int i = tid; i < INC * HID; i += 256) sW[i] = W[i];
    int node0 = blockIdx.x * 4;
    if (tid < 4 * INC) {
        int n = node0 + tid / INC;
        sx[tid / INC][tid % INC] = (n < NN) ? x[n * INC + tid % INC] : 0.0f;
    }
    __syncthreads();
    int n = node0 + (tid >> 6);
    int c = tid & 63;
    if (n < NN) {
        float acc = 0.0f;
#pragma unroll
        for (int k = 0; k < INC; ++k) acc += sx[tid >> 6][k] * sW[k * HID + c];
        out[n * HID + c] = dis[n] * acc;
    }
}

// K = 64 (hidden layers). 4 nodes per 256-thread block; W staged in LDS (16 KB).
__global__ void k_gemm_hid(const float* __restrict__ h, const float* __restrict__ W,
                           const float* __restrict__ dis, float* __restrict__ out) {
    __shared__ float sW[HID * HID];
    __shared__ float sh[4][HID];
    int tid = threadIdx.x;
    for (int i = tid; i < HID * HID; i += 256) sW[i] = W[i];
    int node0 = blockIdx.x * 4;
    {
        int n = node0 + (tid >> 6);
        sh[tid >> 6][tid & 63] = (n < NN) ? h[n * HID + (tid & 63)] : 0.0f;
    }
    __syncthreads();
    int n = node0 + (tid >> 6);
    if (n < NN) {
        int c = tid & 63;
        float acc = 0.0f;
#pragma unroll
        for (int k = 0; k < HID; ++k) acc += sh[tid >> 6][k] * sW[k * HID + c];
        out[n * HID + c] = dis[n] * acc;
    }
}

// ---------------- fused gather + self-loop + bias + (relu) ----------------
// out[d] = act( dis[d] * (hw'[d] + sum_{e in CSR[d]} hw'[src[e]]) + b )
// one wave per node: 64 lanes = 64 channels; csr/rowptr reads are wave-uniform.

template <int RELU>
__global__ void k_gather(const float* __restrict__ hwp, const int* __restrict__ csr,
                         const int* __restrict__ rowptr, const int* __restrict__ cnts,
                         const float* __restrict__ dis, const float* __restrict__ b,
                         float* __restrict__ out) {
    int t = blockIdx.x * blockDim.x + threadIdx.x;
    int d = t >> 6;
    int c = t & 63;
    if (d < NN) {
        float acc = hwp[(size_t)d * HID + c];  // self-loop term (pre-scaled by dis[d])
        int beg = rowptr[d];
        int num = cnts[d];
        for (int j = 0; j < num; ++j) {
            int s = csr[beg + j];
            acc += hwp[(size_t)s * HID + c];
        }
        float v = dis[d] * acc + b[c];
        out[t] = RELU ? fmaxf(v, 0.0f) : v;
    }
}

// ---------------- pooling + head ----------------

#define PNODES 32
// batch is sorted: accumulate runs of equal graph-id in registers, flush on change.
__global__ void k_pool(const float* __restrict__ h, const int* __restrict__ batch,
                       float* __restrict__ sums, float* __restrict__ cnt) {
    int c = threadIdx.x;  // 64 threads = 64 channels
    int n0 = blockIdx.x * PNODES;
    float acc = 0.0f, fc = 0.0f;
    int curg = -1;
    int nend = n0 + PNODES;
    if (nend > NN) nend = NN;
    for (int n = n0; n < nend; ++n) {
        int g = batch[n];
        if (g != curg) {
            if (curg >= 0) {
                atomicAdd(&sums[curg * HID + c], acc);
                if (c == 0) atomicAdd(&cnt[curg], fc);
            }
            acc = 0.0f; fc = 0.0f; curg = g;
        }
        acc += h[n * HID + c];
        fc += 1.0f;
    }
    if (curg >= 0) {
        atomicAdd(&sums[curg * HID + c], acc);
        if (c == 0) atomicAdd(&cnt[curg], fc);
    }
}

__global__ void k_final(const float* __restrict__ sums, const float* __restrict__ cnt,
                        const float* __restrict__ linW, const float* __restrict__ linb,
                        float* __restrict__ out) {
    int t = blockIdx.x * blockDim.x + threadIdx.x;  // NG*OUTC = 2560
    if (t < NG * OUTC) {
        int g = t / OUTC, o = t % OUTC;
        float cmax = fmaxf(cnt[g], 1.0f);
        float acc = linb[o];
#pragma unroll
        for (int k = 0; k < HID; ++k)
            acc += (sums[g * HID + k] / cmax) * linW[k * OUTC + o];
        out[t] = acc;
    }
}

// ---------------- launch ----------------

extern "C" void kernel_launch(void* const* d_in, const int* in_sizes, int n_in,
                              void* d_out, int out_size, void* d_ws, size_t ws_size,
                              hipStream_t stream) {
    const float* x     = (const float*)d_in[0];
    const int*   ei    = (const int*)d_in[1];  // [2, NE]
    const int*   src   = ei;
    const int*   dst   = ei + NE;
    const int*   batch = (const int*)d_in[2];
    const float* W0 = (const float*)d_in[3];
    const float* b0 = (const float*)d_in[4];
    const float* W1 = (const float*)d_in[5];
    const float* b1 = (const float*)d_in[6];
    const float* W2 = (const float*)d_in[7];
    const float* b2 = (const float*)d_in[8];
    const float* linW = (const float*)d_in[9];
    const float* linb = (const float*)d_in[10];
    float* out = (float*)d_out;

    char* ws = (char*)d_ws;
    float* bufA   = (float*)ws;                       ws += sizeof(float) * NN * HID;
    float* bufB   = (float*)ws;                       ws += sizeof(float) * NN * HID;
    float* dis    = (float*)ws;                       ws += sizeof(float) * NN;
    float* sums   = (float*)ws;                       ws += sizeof(float) * NG * HID;
    float* cnt    = (float*)ws;                       ws += sizeof(float) * NG;
    int*   cnts   = (int*)ws;                         ws += sizeof(int) * NN;
    int*   rowptr = (int*)ws;                         ws += sizeof(int) * NN;
    int*   cursor = (int*)ws;                         ws += sizeof(int) * NN;
    int*   bsums  = (int*)ws;                         ws += sizeof(int) * NB_SCAN;
    int*   csr    = (int*)ws;                         ws += sizeof(int) * NE;

    const int TB = 256;
    int gN  = (NN + TB - 1) / TB;
    int gE  = (NE + TB - 1) / TB;
    int gGW = (NN * HID + TB - 1) / TB;  // gather: 1 wave/node
    int gG  = NN / 4;                    // gemm: 4 nodes/block

    // ---- build normalization + CSR (once; reused by all 3 layers) ----
    k_zero<<<gN, TB, 0, stream>>>(cnts, sums, cnt);
    k_count<<<gE, TB, 0, stream>>>(dst, cnts);
    k_dis<<<gN, TB, 0, stream>>>(cnts, dis);
    k_scan1<<<NB_SCAN, 1024, 0, stream>>>(cnts, rowptr, bsums);
    k_scan2<<<1, 64, 0, stream>>>(bsums);
    k_scan3<<<gN, TB, 0, stream>>>(rowptr, bsums, cursor);
    k_fill<<<gE, TB, 0, stream>>>(src, dst, cursor, csr);

    // ---- layer 0 ----
    k_gemm_in<<<gG, TB, 0, stream>>>(x, W0, dis, bufA);
    k_gather<1><<<gGW, TB, 0, stream>>>(bufA, csr, rowptr, cnts, dis, b0, bufB);

    // ---- layer 1 ----
    k_gemm_hid<<<gG, TB, 0, stream>>>(bufB, W1, dis, bufA);
    k_gather<1><<<gGW, TB, 0, stream>>>(bufA, csr, rowptr, cnts, dis, b1, bufB);

    // ---- layer 2 (no relu) ----
    k_gemm_hid<<<gG, TB, 0, stream>>>(bufB, W2, dis, bufA);
    k_gather<0><<<gGW, TB, 0, stream>>>(bufA, csr, rowptr, cnts, dis, b2, bufB);

    // ---- pool + head ----
    k_pool<<<NN / PNODES, HID, 0, stream>>>(bufB, batch, sums, cnt);
    k_final<<<(NG * OUTC + TB - 1) / TB, TB, 0, stream>>>(sums, cnt, linW, linb, out);
}

// Round 3
// 442.951 us; speedup vs baseline: 2.5421x; 1.6437x over previous
//
#include <hip/hip_runtime.h>

#define NN 100000
#define NE 1200000
#define NG 256
#define INC 7
#define HID 64
#define OUTC 10
#define NB_SCAN 98   // ceil(NN/1024)

// ---------------- zero init (ws is poisoned 0xAA before every call) ----------------

__global__ void k_zero(int* __restrict__ cnts, float* __restrict__ sums,
                       float* __restrict__ cnt) {
    int i = blockIdx.x * blockDim.x + threadIdx.x;
    if (i < NN) cnts[i] = 0;
    if (i < NG * 16) sums[i] = 0.0f;
    if (i < NG) cnt[i] = 0.0f;
}

// ---------------- degree histogram + normalization ----------------

__global__ void k_count(const int* __restrict__ dst, int* __restrict__ cnts) {
    int e = blockIdx.x * blockDim.x + threadIdx.x;
    if (e < NE) atomicAdd(&cnts[dst[e]], 1);
}

__global__ void k_dis(const int* __restrict__ cnts, float* __restrict__ dis) {
    int i = blockIdx.x * blockDim.x + threadIdx.x;
    if (i < NN) dis[i] = rsqrtf((float)cnts[i] + 1.0f);  // +1 = self-loop
}

// ---------------- exclusive scan (3-pass) ----------------

__global__ __launch_bounds__(1024) void k_scan1(const int* __restrict__ cnts,
                                                int* __restrict__ rowptr,
                                                int* __restrict__ blocksums) {
    __shared__ int tmp[1024];
    int tid = threadIdx.x;
    int i = blockIdx.x * 1024 + tid;
    int v = (i < NN) ? cnts[i] : 0;
    tmp[tid] = v;
    __syncthreads();
    for (int off = 1; off < 1024; off <<= 1) {
        int add = (tid >= off) ? tmp[tid - off] : 0;
        __syncthreads();
        tmp[tid] += add;
        __syncthreads();
    }
    if (i < NN) rowptr[i] = tmp[tid] - v;  // exclusive
    if (tid == 1023) blocksums[blockIdx.x] = tmp[1023];
}

__global__ void k_scan2(int* __restrict__ bs) {  // tiny serial scan of 98 block sums
    if (threadIdx.x == 0 && blockIdx.x == 0) {
        int acc = 0;
        for (int i = 0; i < NB_SCAN; ++i) { int t = bs[i]; bs[i] = acc; acc += t; }
    }
}

__global__ void k_scan3(int* __restrict__ rowptr, const int* __restrict__ bs,
                        int* __restrict__ cursor) {
    int i = blockIdx.x * blockDim.x + threadIdx.x;
    if (i < NN) {
        int r = rowptr[i] + bs[i >> 10];
        rowptr[i] = r;
        cursor[i] = r;
    }
}

// ---------------- CSR fill ----------------

__global__ void k_fill(const int* __restrict__ src, const int* __restrict__ dst,
                       int* __restrict__ cursor, int* __restrict__ csr) {
    int e = blockIdx.x * blockDim.x + threadIdx.x;
    if (e < NE) {
        int p = atomicAdd(&cursor[dst[e]], 1);
        csr[p] = src[e];
    }
}

// ---------------- layer 0: (A^ x) W0  — gather first on 8 channels ----------------

// xp[n][c] = dis[n]*x[n][c] for c<7, 0 for c==7
__global__ void k_prep_x(const float* __restrict__ x, const float* __restrict__ dis,
                         float* __restrict__ xp) {
    int t = blockIdx.x * blockDim.x + threadIdx.x;
    if (t < NN * 8) {
        int n = t >> 3, c = t & 7;
        xp[t] = (c < INC) ? dis[n] * x[n * INC + c] : 0.0f;
    }
}

// aggx[d] = dis[d] * (xp[d] + sum_in xp[s])   (8 lanes per node)
__global__ void k_gather8(const float* __restrict__ xp, const int* __restrict__ csr,
                          const int* __restrict__ rowptr, const int* __restrict__ cnts,
                          const float* __restrict__ dis, float* __restrict__ aggx) {
    int t = blockIdx.x * blockDim.x + threadIdx.x;
    int d = t >> 3, c = t & 7;
    if (d >= NN) return;
    int beg = rowptr[d], num = cnts[d];
    float acc = xp[(size_t)d * 8 + c];
    int j = 0;
    while (j < num) {
        int chunk = min(num - j, 8);
        int iv = (c < chunk) ? csr[beg + j + c] : 0;
        for (int k = 0; k < chunk; ++k) {
            int s = __shfl(iv, k, 8);
            acc += xp[(size_t)s * 8 + c];
        }
        j += chunk;
    }
    aggx[(size_t)d * 8 + c] = dis[d] * acc;
}

// h0 = relu(aggx(:,0:7) @ W0 + b0)
__global__ void k_gemm8(const float* __restrict__ aggx, const float* __restrict__ W0,
                        const float* __restrict__ b0, float* __restrict__ h0) {
    __shared__ float sW[INC * HID];
    __shared__ float sx[4][8];
    int tid = threadIdx.x;
    for (int i = tid; i < INC * HID; i += 256) sW[i] = W0[i];
    int node0 = blockIdx.x * 4;
    if (tid < 32) {
        int n = node0 + (tid >> 3);
        sx[tid >> 3][tid & 7] = (n < NN) ? aggx[(size_t)n * 8 + (tid & 7)] : 0.0f;
    }
    __syncthreads();
    int n = node0 + (tid >> 6), c = tid & 63;
    if (n < NN) {
        float acc = b0[c];
#pragma unroll
        for (int k = 0; k < INC; ++k) acc += sx[tid >> 6][k] * sW[k * HID + c];
        h0[(size_t)n * HID + c] = fmaxf(acc, 0.0f);
    }
}

// ---------------- layer 1: hidden GEMM (epilogue * dis) + 64-ch gather ----------------

__global__ void k_gemm_hid(const float* __restrict__ h, const float* __restrict__ W,
                           const float* __restrict__ dis, float* __restrict__ out) {
    __shared__ float sW[HID * HID];
    __shared__ float sh[4][HID + 1];  // +1 pad: avoid 4-way bank conflict
    int tid = threadIdx.x;
    for (int i = tid; i < HID * HID; i += 256) sW[i] = W[i];
    int node0 = blockIdx.x * 4;
    {
        int n = node0 + (tid >> 6);
        sh[tid >> 6][tid & 63] = (n < NN) ? h[(size_t)n * HID + (tid & 63)] : 0.0f;
    }
    __syncthreads();
    int n = node0 + (tid >> 6);
    if (n < NN) {
        int c = tid & 63;
        float acc = 0.0f;
#pragma unroll
        for (int k = 0; k < HID; ++k) acc += sh[tid >> 6][k] * sW[k * HID + c];
        out[(size_t)n * HID + c] = dis[n] * acc;
    }
}

// out[d] = relu( dis[d] * (hwp[d] + sum_in hwp[s]) + b )
// one wave per node; csr indices vector-loaded then shfl-broadcast; 4-way MLP unroll
__global__ void k_gather64(const float* __restrict__ hwp, const int* __restrict__ csr,
                           const int* __restrict__ rowptr, const int* __restrict__ cnts,
                           const float* __restrict__ dis, const float* __restrict__ b,
                           float* __restrict__ out) {
    int t = blockIdx.x * blockDim.x + threadIdx.x;
    int d = t >> 6, c = t & 63;
    if (d >= NN) return;
    int beg = rowptr[d], num = cnts[d];
    float acc0 = hwp[(size_t)d * HID + c];
    float acc1 = 0.0f, acc2 = 0.0f, acc3 = 0.0f;
    int nv = (num < 64) ? num : 64;
    int iv = (c < nv) ? csr[beg + c] : 0;
    int j = 0;
    for (; j + 4 <= nv; j += 4) {
        int s0 = __shfl(iv, j);
        int s1 = __shfl(iv, j + 1);
        int s2 = __shfl(iv, j + 2);
        int s3 = __shfl(iv, j + 3);
        acc0 += hwp[(size_t)s0 * HID + c];
        acc1 += hwp[(size_t)s1 * HID + c];
        acc2 += hwp[(size_t)s2 * HID + c];
        acc3 += hwp[(size_t)s3 * HID + c];
    }
    for (; j < nv; ++j) {
        int s = __shfl(iv, j);
        acc0 += hwp[(size_t)s * HID + c];
    }
    for (; j < num; ++j) {  // degree > 64: essentially never, but correct
        int s = csr[beg + j];
        acc0 += hwp[(size_t)s * HID + c];
    }
    float v = dis[d] * ((acc0 + acc1) + (acc2 + acc3)) + b[c];
    out[t] = fmaxf(v, 0.0f);
}

// ---------------- layer 2 folded with head: Wc = W2 @ linW, bc = b2 @ linW + linb ----

__global__ void k_wc(const float* __restrict__ W2, const float* __restrict__ linW,
                     const float* __restrict__ b2, const float* __restrict__ linb,
                     float* __restrict__ Wc, float* __restrict__ bc) {
    int t = threadIdx.x;
    for (int i = t; i < HID * 16; i += 256) {
        int k = i >> 4, o = i & 15;
        float acc = 0.0f;
        if (o < OUTC)
            for (int q = 0; q < HID; ++q) acc += W2[k * HID + q] * linW[q * OUTC + o];
        Wc[i] = acc;
    }
    if (t < 16) {
        float acc = 0.0f;
        if (t < OUTC) {
            acc = linb[t];
            for (int q = 0; q < HID; ++q) acc += b2[q] * linW[q * OUTC + t];
        }
        bc[t] = acc;
    }
}

// z = dis ⊙ (h1 @ Wc)  [NN x 16, cols 10..15 zero]; 16 nodes per 256-thread block
__global__ void k_gemm_z(const float* __restrict__ h, const float* __restrict__ Wc,
                         const float* __restrict__ dis, float* __restrict__ z) {
    __shared__ float sW[HID * 16];
    __shared__ float sh[16][HID + 1];  // pad: avoid 4-way conflict on broadcast reads
    int tid = threadIdx.x;
    for (int i = tid; i < HID * 16; i += 256) sW[i] = Wc[i];
    int node0 = blockIdx.x * 16;
    for (int i = tid; i < 16 * HID; i += 256) {
        int nsub = i >> 6, k = i & 63;
        int n = node0 + nsub;
        sh[nsub][k] = (n < NN) ? h[(size_t)n * HID + k] : 0.0f;
    }
    __syncthreads();
    int nsub = tid >> 4, c = tid & 15;
    int n = node0 + nsub;
    if (n < NN) {
        float acc = 0.0f;
        if (c < OUTC) {
#pragma unroll
            for (int k = 0; k < HID; ++k) acc += sh[nsub][k] * sW[k * 16 + c];
            acc *= dis[n];
        }
        z[(size_t)n * 16 + c] = acc;
    }
}

// agg2[d] = dis[d] * (z[d] + sum_in z[s])   (16 lanes per node)
__global__ void k_gather16(const float* __restrict__ z, const int* __restrict__ csr,
                           const int* __restrict__ rowptr, const int* __restrict__ cnts,
                           const float* __restrict__ dis, float* __restrict__ agg2) {
    int t = blockIdx.x * blockDim.x + threadIdx.x;
    int d = t >> 4, c = t & 15;
    if (d >= NN) return;
    int beg = rowptr[d], num = cnts[d];
    float acc = z[(size_t)d * 16 + c];
    int j = 0;
    while (j < num) {
        int chunk = min(num - j, 16);
        int iv = (c < chunk) ? csr[beg + j + c] : 0;
        for (int k = 0; k < chunk; ++k) {
            int s = __shfl(iv, k, 16);
            acc += z[(size_t)s * 16 + c];
        }
        j += chunk;
    }
    agg2[(size_t)d * 16 + c] = dis[d] * acc;
}

// ---------------- pooling (16 ch) + head ----------------

#define PN 32
__global__ void k_pool16(const float* __restrict__ agg2, const int* __restrict__ batch,
                         float* __restrict__ sums, float* __restrict__ cnt) {
    int c = threadIdx.x & 15;
    int sub = threadIdx.x >> 4;  // 0..3
    int n0 = (blockIdx.x * 4 + sub) * PN;
    float acc = 0.0f, fc = 0.0f;
    int curg = -1;
    int nend = n0 + PN;
    if (nend > NN) nend = NN;
    for (int n = n0; n < nend; ++n) {
        int g = batch[n];
        if (g != curg) {
            if (curg >= 0) {
                atomicAdd(&sums[curg * 16 + c], acc);
                if (c == 0) atomicAdd(&cnt[curg], fc);
            }
            acc = 0.0f; fc = 0.0f; curg = g;
        }
        acc += agg2[(size_t)n * 16 + c];
        fc += 1.0f;
    }
    if (curg >= 0) {
        atomicAdd(&sums[curg * 16 + c], acc);
        if (c == 0) atomicAdd(&cnt[curg], fc);
    }
}

__global__ void k_final2(const float* __restrict__ sums, const float* __restrict__ cnt,
                         const float* __restrict__ bc, float* __restrict__ out) {
    int t = blockIdx.x * blockDim.x + threadIdx.x;
    if (t < NG * OUTC) {
        int g = t / OUTC, o = t % OUTC;
        out[t] = sums[g * 16 + o] / fmaxf(cnt[g], 1.0f) + bc[o];
    }
}

// ---------------- launch ----------------

extern "C" void kernel_launch(void* const* d_in, const int* in_sizes, int n_in,
                              void* d_out, int out_size, void* d_ws, size_t ws_size,
                              hipStream_t stream) {
    const float* x     = (const float*)d_in[0];
    const int*   ei    = (const int*)d_in[1];  // [2, NE]
    const int*   src   = ei;
    const int*   dst   = ei + NE;
    const int*   batch = (const int*)d_in[2];
    const float* W0 = (const float*)d_in[3];
    const float* b0 = (const float*)d_in[4];
    const float* W1 = (const float*)d_in[5];
    const float* b1 = (const float*)d_in[6];
    const float* W2 = (const float*)d_in[7];
    const float* b2 = (const float*)d_in[8];
    const float* linW = (const float*)d_in[9];
    const float* linb = (const float*)d_in[10];
    float* out = (float*)d_out;

    char* ws = (char*)d_ws;
    float* bufA   = (float*)ws;                 ws += sizeof(float) * NN * HID;
    float* bufB   = (float*)ws;                 ws += sizeof(float) * NN * HID;
    float* dis    = (float*)ws;                 ws += sizeof(float) * NN;
    float* sums   = (float*)ws;                 ws += sizeof(float) * NG * 16;
    float* cnt    = (float*)ws;                 ws += sizeof(float) * NG;
    float* Wc     = (float*)ws;                 ws += sizeof(float) * HID * 16;
    float* bc     = (float*)ws;                 ws += sizeof(float) * 16;
    int*   cnts   = (int*)ws;                   ws += sizeof(int) * NN;
    int*   rowptr = (int*)ws;                   ws += sizeof(int) * NN;
    int*   cursor = (int*)ws;                   ws += sizeof(int) * NN;
    int*   bsums  = (int*)ws;                   ws += sizeof(int) * NB_SCAN;
    int*   csr    = (int*)ws;                   ws += sizeof(int) * NE;

    // aliases (lifetimes don't overlap):
    float* xp   = bufA;               // [NN*8]   layer-0 prescaled input
    float* aggx = bufA + NN * 8;      // [NN*8]   layer-0 aggregate
    float* h0   = bufB;               // [NN*64]
    float* hwp  = bufA;               // [NN*64]  layer-1 prescaled h@W1
    float* h1   = bufB;               // [NN*64]
    float* zz   = bufA;               // [NN*16]  layer-2 folded features
    float* agg2 = bufB;               // [NN*16]

    const int TB = 256;
    int gN = (NN + TB - 1) / TB;
    int gE = (NE + TB - 1) / TB;

    // ---- normalization + CSR (reused by all layers) ----
    k_zero<<<gN, TB, 0, stream>>>(cnts, sums, cnt);
    k_count<<<gE, TB, 0, stream>>>(dst, cnts);
    k_dis<<<gN, TB, 0, stream>>>(cnts, dis);
    k_scan1<<<NB_SCAN, 1024, 0, stream>>>(cnts, rowptr, bsums);
    k_scan2<<<1, 64, 0, stream>>>(bsums);
    k_scan3<<<gN, TB, 0, stream>>>(rowptr, bsums, cursor);
    k_fill<<<gE, TB, 0, stream>>>(src, dst, cursor, csr);

    // ---- layer 0: gather(8ch) then transform ----
    k_prep_x<<<(NN * 8 + TB - 1) / TB, TB, 0, stream>>>(x, dis, xp);
    k_gather8<<<(NN * 8 + TB - 1) / TB, TB, 0, stream>>>(xp, csr, rowptr, cnts, dis, aggx);
    k_gemm8<<<(NN + 3) / 4, TB, 0, stream>>>(aggx, W0, b0, h0);

    // ---- layer 1: transform then gather(64ch) ----
    k_gemm_hid<<<(NN + 3) / 4, TB, 0, stream>>>(h0, W1, dis, hwp);
    k_gather64<<<(NN * HID + TB - 1) / TB, TB, 0, stream>>>(hwp, csr, rowptr, cnts, dis, b1, h1);

    // ---- layer 2 folded with linear head: 16-ch pipeline ----
    k_wc<<<1, TB, 0, stream>>>(W2, linW, b2, linb, Wc, bc);
    k_gemm_z<<<(NN + 15) / 16, TB, 0, stream>>>(h1, Wc, dis, zz);
    k_gather16<<<(NN * 16 + TB - 1) / TB, TB, 0, stream>>>(zz, csr, rowptr, cnts, dis, agg2);

    // ---- pool + head ----
    k_pool16<<<(NN + 4 * PN - 1) / (4 * PN), 64, 0, stream>>>(agg2, batch, sums, cnt);
    k_final2<<<(NG * OUTC + TB - 1) / TB, TB, 0, stream>>>(sums, cnt, bc, out);
}

// Round 5
// 350.079 us; speedup vs baseline: 3.2165x; 1.2653x over previous
//
#include <hip/hip_runtime.h>

#define NN 100000
#define NE 1200000
#define NG 256
#define INC 7
#define HID 64
#define OUTC 10

#define NBKT 196          // ceil(NN / 512) buckets of 512 nodes
#define BCAP 8192         // per-bucket capacity (avg 6144, sigma ~78)
#define BIN_CHUNK 16384   // edges per k_bin block
#define NBIN_BLK ((NE + BIN_CHUNK - 1) / BIN_CHUNK)  // 74

// ---------------- zero init (ws is poisoned 0xAA before every call) ----------------

__global__ void k_zero(float* __restrict__ sums, float* __restrict__ cnt,
                       int* __restrict__ bktcur) {
    int i = blockIdx.x * blockDim.x + threadIdx.x;
    if (i < NG * 16) sums[i] = 0.0f;
    if (i < NG) cnt[i] = 0.0f;
    if (i < NBKT) bktcur[i] = 0;
}

// ---------------- pass B: bin edges by dst>>9, packed (src<<9)|(dst&511) ----------------

__global__ __launch_bounds__(1024) void k_bin(const int* __restrict__ src,
                                              const int* __restrict__ dst,
                                              int* __restrict__ bktcur,
                                              unsigned int* __restrict__ binned) {
    __shared__ int hcnt[NBKT];
    __shared__ int hbase[NBKT];
    int tid = threadIdx.x;
    int e0 = blockIdx.x * BIN_CHUNK;
    int lim = NE - e0; if (lim > BIN_CHUNK) lim = BIN_CHUNK;

    for (int b = tid; b < NBKT; b += 1024) hcnt[b] = 0;
    __syncthreads();
    // phase 1: count
    for (int i = tid; i < lim; i += 1024) {
        atomicAdd(&hcnt[dst[e0 + i] >> 9], 1);
    }
    __syncthreads();
    // reserve contiguous runs in each bucket
    for (int b = tid; b < NBKT; b += 1024) {
        int c = hcnt[b];
        hbase[b] = c ? atomicAdd(&bktcur[b], c) : 0;
        hcnt[b] = 0;  // reuse as intra-block rank counter
    }
    __syncthreads();
    // phase 2: scatter (dense runs per bucket)
    for (int i = tid; i < lim; i += 1024) {
        int d = dst[e0 + i];
        int s = src[e0 + i];
        int b = d >> 9;
        int r = atomicAdd(&hcnt[b], 1);
        binned[(size_t)b * BCAP + hbase[b] + r] = ((unsigned int)s << 9) | (d & 511);
    }
}

// ---------------- bucket base scan (196 values) ----------------

__global__ void k_bktscan(const int* __restrict__ bktcur, int* __restrict__ bktbase) {
    __shared__ int sa[256], sb[256];
    int t = threadIdx.x;
    int v = (t < NBKT) ? bktcur[t] : 0;
    sa[t] = v;
    __syncthreads();
    int* p = sa; int* q = sb;
    for (int off = 1; off < 256; off <<= 1) {
        q[t] = p[t] + ((t >= off) ? p[t - off] : 0);
        __syncthreads();
        int* tmp = p; p = q; q = tmp;
    }
    if (t < NBKT) bktbase[t] = p[t] - v;  // exclusive
}

// ---------------- pass C: per-bucket exact CSR + cnts + rowptr + dis ----------------

__global__ void k_build(const unsigned int* __restrict__ binned,
                        const int* __restrict__ bktcur, const int* __restrict__ bktbase,
                        int* __restrict__ csr, int* __restrict__ rowptr,
                        int* __restrict__ cnts, float* __restrict__ dis) {
    __shared__ int lcnt[512];
    __shared__ int lcur[512];
    __shared__ int sa[512], sb[512];
    int b = blockIdx.x;
    int tid = threadIdx.x;  // 256 threads
    int nbase = b << 9;
    int nnum = NN - nbase; if (nnum > 512) nnum = 512;
    int m = bktcur[b];
    int base = bktbase[b];
    const unsigned int* bp = binned + (size_t)b * BCAP;

    for (int n = tid; n < 512; n += 256) lcnt[n] = 0;
    __syncthreads();
    for (int i = tid; i < m; i += 256) atomicAdd(&lcnt[bp[i] & 511], 1);
    __syncthreads();
    // inclusive Hillis-Steele scan over 512 in LDS
    for (int n = tid; n < 512; n += 256) sa[n] = lcnt[n];
    __syncthreads();
    int* p = sa; int* q = sb;
    for (int off = 1; off < 512; off <<= 1) {
        for (int n = tid; n < 512; n += 256)
            q[n] = p[n] + ((n >= off) ? p[n - off] : 0);
        __syncthreads();
        int* tmp = p; p = q; q = tmp;
    }
    // exclusive prefix = inclusive - self
    for (int n = tid; n < 512; n += 256) {
        int pre = p[n] - lcnt[n];
        lcur[n] = pre;
        if (n < nnum) {
            int c = lcnt[n];
            rowptr[nbase + n] = base + pre;
            cnts[nbase + n] = c;
            dis[nbase + n] = rsqrtf((float)c + 1.0f);
        }
    }
    __syncthreads();
    // scatter srcs into exact CSR slots (dense 4B*m region)
    for (int i = tid; i < m; i += 256) {
        unsigned int pk = bp[i];
        int ld = pk & 511;
        int s = (int)(pk >> 9);
        int r = atomicAdd(&lcur[ld], 1);
        csr[base + r] = s;
    }
}

// ---------------- layer 0: (A^ x) W0  — gather first on 8 channels ----------------

__global__ void k_prep_x(const float* __restrict__ x, const float* __restrict__ dis,
                         float* __restrict__ xp) {
    int t = blockIdx.x * blockDim.x + threadIdx.x;
    if (t < NN * 8) {
        int n = t >> 3, c = t & 7;
        xp[t] = (c < INC) ? dis[n] * x[n * INC + c] : 0.0f;
    }
}

__global__ void k_gather8(const float* __restrict__ xp, const int* __restrict__ csr,
                          const int* __restrict__ rowptr, const int* __restrict__ cnts,
                          const float* __restrict__ dis, float* __restrict__ aggx) {
    int t = blockIdx.x * blockDim.x + threadIdx.x;
    int d = t >> 3, c = t & 7;
    if (d >= NN) return;
    int beg = rowptr[d], num = cnts[d];
    float acc = xp[(size_t)d * 8 + c];
    int j = 0;
    while (j < num) {
        int chunk = min(num - j, 8);
        int iv = (c < chunk) ? csr[beg + j + c] : 0;
        for (int k = 0; k < chunk; ++k) {
            int s = __shfl(iv, k, 8);
            acc += xp[(size_t)s * 8 + c];
        }
        j += chunk;
    }
    aggx[(size_t)d * 8 + c] = dis[d] * acc;
}

__global__ void k_gemm8(const float* __restrict__ aggx, const float* __restrict__ W0,
                        const float* __restrict__ b0, float* __restrict__ h0) {
    __shared__ float sW[INC * HID];
    __shared__ float sx[4][8];
    int tid = threadIdx.x;
    for (int i = tid; i < INC * HID; i += 256) sW[i] = W0[i];
    int node0 = blockIdx.x * 4;
    if (tid < 32) {
        int n = node0 + (tid >> 3);
        sx[tid >> 3][tid & 7] = (n < NN) ? aggx[(size_t)n * 8 + (tid & 7)] : 0.0f;
    }
    __syncthreads();
    int n = node0 + (tid >> 6), c = tid & 63;
    if (n < NN) {
        float acc = b0[c];
#pragma unroll
        for (int k = 0; k < INC; ++k) acc += sx[tid >> 6][k] * sW[k * HID + c];
        h0[(size_t)n * HID + c] = fmaxf(acc, 0.0f);
    }
}

// ---------------- layer 1: hidden GEMM (epilogue * dis) + 64-ch gather ----------------

__global__ void k_gemm_hid(const float* __restrict__ h, const float* __restrict__ W,
                           const float* __restrict__ dis, float* __restrict__ out) {
    __shared__ float sW[HID * HID];
    __shared__ float sh[4][HID + 1];
    int tid = threadIdx.x;
    for (int i = tid; i < HID * HID; i += 256) sW[i] = W[i];
    int node0 = blockIdx.x * 4;
    {
        int n = node0 + (tid >> 6);
        sh[tid >> 6][tid & 63] = (n < NN) ? h[(size_t)n * HID + (tid & 63)] : 0.0f;
    }
    __syncthreads();
    int n = node0 + (tid >> 6);
    if (n < NN) {
        int c = tid & 63;
        float acc = 0.0f;
#pragma unroll
        for (int k = 0; k < HID; ++k) acc += sh[tid >> 6][k] * sW[k * HID + c];
        out[(size_t)n * HID + c] = dis[n] * acc;
    }
}

__global__ void k_gather64(const float* __restrict__ hwp, const int* __restrict__ csr,
                           const int* __restrict__ rowptr, const int* __restrict__ cnts,
                           const float* __restrict__ dis, const float* __restrict__ b,
                           float* __restrict__ out) {
    int t = blockIdx.x * blockDim.x + threadIdx.x;
    int d = t >> 6, c = t & 63;
    if (d >= NN) return;
    int beg = rowptr[d], num = cnts[d];
    float acc0 = hwp[(size_t)d * HID + c];
    float acc1 = 0.0f, acc2 = 0.0f, acc3 = 0.0f;
    int nv = (num < 64) ? num : 64;
    int iv = (c < nv) ? csr[beg + c] : 0;
    int j = 0;
    for (; j + 4 <= nv; j += 4) {
        int s0 = __shfl(iv, j);
        int s1 = __shfl(iv, j + 1);
        int s2 = __shfl(iv, j + 2);
        int s3 = __shfl(iv, j + 3);
        acc0 += hwp[(size_t)s0 * HID + c];
        acc1 += hwp[(size_t)s1 * HID + c];
        acc2 += hwp[(size_t)s2 * HID + c];
        acc3 += hwp[(size_t)s3 * HID + c];
    }
    for (; j < nv; ++j) {
        int s = __shfl(iv, j);
        acc0 += hwp[(size_t)s * HID + c];
    }
    for (; j < num; ++j) {
        int s = csr[beg + j];
        acc0 += hwp[(size_t)s * HID + c];
    }
    float v = dis[d] * ((acc0 + acc1) + (acc2 + acc3)) + b[c];
    out[t] = fmaxf(v, 0.0f);
}

// ---------------- layer 2 folded with head ----------------

__global__ void k_wc(const float* __restrict__ W2, const float* __restrict__ linW,
                     const float* __restrict__ b2, const float* __restrict__ linb,
                     float* __restrict__ Wc, float* __restrict__ bc) {
    int t = threadIdx.x;
    for (int i = t; i < HID * 16; i += 256) {
        int k = i >> 4, o = i & 15;
        float acc = 0.0f;
        if (o < OUTC)
            for (int q = 0; q < HID; ++q) acc += W2[k * HID + q] * linW[q * OUTC + o];
        Wc[i] = acc;
    }
    if (t < 16) {
        float acc = 0.0f;
        if (t < OUTC) {
            acc = linb[t];
            for (int q = 0; q < HID; ++q) acc += b2[q] * linW[q * OUTC + t];
        }
        bc[t] = acc;
    }
}

__global__ void k_gemm_z(const float* __restrict__ h, const float* __restrict__ Wc,
                         const float* __restrict__ dis, float* __restrict__ z) {
    __shared__ float sW[HID * 16];
    __shared__ float sh[16][HID + 1];
    int tid = threadIdx.x;
    for (int i = tid; i < HID * 16; i += 256) sW[i] = Wc[i];
    int node0 = blockIdx.x * 16;
    for (int i = tid; i < 16 * HID; i += 256) {
        int nsub = i >> 6, k = i & 63;
        int n = node0 + nsub;
        sh[nsub][k] = (n < NN) ? h[(size_t)n * HID + k] : 0.0f;
    }
    __syncthreads();
    int nsub = tid >> 4, c = tid & 15;
    int n = node0 + nsub;
    if (n < NN) {
        float acc = 0.0f;
        if (c < OUTC) {
#pragma unroll
            for (int k = 0; k < HID; ++k) acc += sh[nsub][k] * sW[k * 16 + c];
            acc *= dis[n];
        }
        z[(size_t)n * 16 + c] = acc;
    }
}

__global__ void k_gather16(const float* __restrict__ z, const int* __restrict__ csr,
                           const int* __restrict__ rowptr, const int* __restrict__ cnts,
                           const float* __restrict__ dis, float* __restrict__ agg2) {
    int t = blockIdx.x * blockDim.x + threadIdx.x;
    int d = t >> 4, c = t & 15;
    if (d >= NN) return;
    int beg = rowptr[d], num = cnts[d];
    float acc = z[(size_t)d * 16 + c];
    int j = 0;
    while (j < num) {
        int chunk = min(num - j, 16);
        int iv = (c < chunk) ? csr[beg + j + c] : 0;
        for (int k = 0; k < chunk; ++k) {
            int s = __shfl(iv, k, 16);
            acc += z[(size_t)s * 16 + c];
        }
        j += chunk;
    }
    agg2[(size_t)d * 16 + c] = dis[d] * acc;
}

// ---------------- pooling (16 ch) + head ----------------

#define PN 32
__global__ void k_pool16(const float* __restrict__ agg2, const int* __restrict__ batch,
                         float* __restrict__ sums, float* __restrict__ cnt) {
    int c = threadIdx.x & 15;
    int sub = threadIdx.x >> 4;
    int n0 = (blockIdx.x * 4 + sub) * PN;
    float acc = 0.0f, fc = 0.0f;
    int curg = -1;
    int nend = n0 + PN;
    if (nend > NN) nend = NN;
    for (int n = n0; n < nend; ++n) {
        int g = batch[n];
        if (g != curg) {
            if (curg >= 0) {
                atomicAdd(&sums[curg * 16 + c], acc);
                if (c == 0) atomicAdd(&cnt[curg], fc);
            }
            acc = 0.0f; fc = 0.0f; curg = g;
        }
        acc += agg2[(size_t)n * 16 + c];
        fc += 1.0f;
    }
    if (curg >= 0) {
        atomicAdd(&sums[curg * 16 + c], acc);
        if (c == 0) atomicAdd(&cnt[curg], fc);
    }
}

__global__ void k_final2(const float* __restrict__ sums, const float* __restrict__ cnt,
                         const float* __restrict__ bc, float* __restrict__ out) {
    int t = blockIdx.x * blockDim.x + threadIdx.x;
    if (t < NG * OUTC) {
        int g = t / OUTC, o = t % OUTC;
        out[t] = sums[g * 16 + o] / fmaxf(cnt[g], 1.0f) + bc[o];
    }
}

// ---------------- launch ----------------

extern "C" void kernel_launch(void* const* d_in, const int* in_sizes, int n_in,
                              void* d_out, int out_size, void* d_ws, size_t ws_size,
                              hipStream_t stream) {
    const float* x     = (const float*)d_in[0];
    const int*   ei    = (const int*)d_in[1];  // [2, NE]
    const int*   src   = ei;
    const int*   dst   = ei + NE;
    const int*   batch = (const int*)d_in[2];
    const float* W0 = (const float*)d_in[3];
    const float* b0 = (const float*)d_in[4];
    const float* W1 = (const float*)d_in[5];
    const float* b1 = (const float*)d_in[6];
    const float* W2 = (const float*)d_in[7];
    const float* b2 = (const float*)d_in[8];
    const float* linW = (const float*)d_in[9];
    const float* linb = (const float*)d_in[10];
    float* out = (float*)d_out;

    char* ws = (char*)d_ws;
    float* bufA    = (float*)ws;               ws += sizeof(float) * NN * HID;
    float* bufB    = (float*)ws;               ws += sizeof(float) * NN * HID;
    float* dis     = (float*)ws;               ws += sizeof(float) * NN;
    float* sums    = (float*)ws;               ws += sizeof(float) * NG * 16;
    float* cnt     = (float*)ws;               ws += sizeof(float) * NG;
    float* Wc      = (float*)ws;               ws += sizeof(float) * HID * 16;
    float* bc      = (float*)ws;               ws += sizeof(float) * 16;
    int*   cnts    = (int*)ws;                 ws += sizeof(int) * NN;
    int*   rowptr  = (int*)ws;                 ws += sizeof(int) * NN;
    int*   bktcur  = (int*)ws;                 ws += sizeof(int) * NBKT;
    int*   bktbase = (int*)ws;                 ws += sizeof(int) * NBKT;
    int*   csr     = (int*)ws;                 ws += sizeof(int) * NE;

    // aliases (lifetimes disjoint):
    unsigned int* binned = (unsigned int*)bufA;  // [NBKT*BCAP] = 6.4 MB, dead before prep_x
    float* xp   = bufA;               // [NN*8]
    float* aggx = bufA + NN * 8;      // [NN*8]
    float* h0   = bufB;               // [NN*64]
    float* hwp  = bufA;               // [NN*64]
    float* h1   = bufB;               // [NN*64]
    float* zz   = bufA;               // [NN*16]
    float* agg2 = bufB;               // [NN*16]

    const int TB = 256;

    // ---- CSR + normalization build (counting sort, dense writes) ----
    k_zero<<<16, TB, 0, stream>>>(sums, cnt, bktcur);
    k_bin<<<NBIN_BLK, 1024, 0, stream>>>(src, dst, bktcur, binned);
    k_bktscan<<<1, TB, 0, stream>>>(bktcur, bktbase);
    k_build<<<NBKT, TB, 0, stream>>>(binned, bktcur, bktbase, csr, rowptr, cnts, dis);

    // ---- layer 0: gather(8ch) then transform ----
    k_prep_x<<<(NN * 8 + TB - 1) / TB, TB, 0, stream>>>(x, dis, xp);
    k_gather8<<<(NN * 8 + TB - 1) / TB, TB, 0, stream>>>(xp, csr, rowptr, cnts, dis, aggx);
    k_gemm8<<<(NN + 3) / 4, TB, 0, stream>>>(aggx, W0, b0, h0);

    // ---- layer 1: transform then gather(64ch) ----
    k_gemm_hid<<<(NN + 3) / 4, TB, 0, stream>>>(h0, W1, dis, hwp);
    k_gather64<<<(NN * HID + TB - 1) / TB, TB, 0, stream>>>(hwp, csr, rowptr, cnts, dis, b1, h1);

    // ---- layer 2 folded with linear head: 16-ch pipeline ----
    k_wc<<<1, TB, 0, stream>>>(W2, linW, b2, linb, Wc, bc);
    k_gemm_z<<<(NN + 15) / 16, TB, 0, stream>>>(h1, Wc, dis, zz);
    k_gather16<<<(NN * 16 + TB - 1) / TB, TB, 0, stream>>>(zz, csr, rowptr, cnts, dis, agg2);

    // ---- pool + head ----
    k_pool16<<<(NN + 4 * PN - 1) / (4 * PN), 64, 0, stream>>>(agg2, batch, sums, cnt);
    k_final2<<<(NG * OUTC + TB - 1) / TB, TB, 0, stream>>>(sums, cnt, bc, out);
}

// Round 6
// 303.228 us; speedup vs baseline: 3.7134x; 1.1545x over previous
//
#include <hip/hip_runtime.h>

#define NN 100000
#define NE 1200000
#define NG 256
#define INC 7
#define HID 64
#define OUTC 10

#define NBKT 196          // ceil(NN / 512) buckets of 512 nodes
#define BCAP 8192         // per-bucket capacity (avg 6144)
#define BIN_CHUNK 16384   // edges per k_bin block
#define NBIN_BLK ((NE + BIN_CHUNK - 1) / BIN_CHUNK)  // 74

// ---------------- zero init (ws is poisoned 0xAA before every call) ----------------

__global__ void k_zero(float* __restrict__ sums, float* __restrict__ cnt,
                       int* __restrict__ bktcur) {
    int i = blockIdx.x * blockDim.x + threadIdx.x;
    if (i < NG * 16) sums[i] = 0.0f;
    if (i < NG) cnt[i] = 0.0f;
    if (i < NBKT) bktcur[i] = 0;
}

// ---------------- pass B: bin edges by dst>>9, packed (src<<9)|(dst&511) ----------------

__global__ __launch_bounds__(1024) void k_bin(const int* __restrict__ src,
                                              const int* __restrict__ dst,
                                              int* __restrict__ bktcur,
                                              unsigned int* __restrict__ binned) {
    __shared__ int hcnt[NBKT];
    __shared__ int hbase[NBKT];
    int tid = threadIdx.x;
    int e0 = blockIdx.x * BIN_CHUNK;
    int lim = NE - e0; if (lim > BIN_CHUNK) lim = BIN_CHUNK;

    for (int b = tid; b < NBKT; b += 1024) hcnt[b] = 0;
    __syncthreads();
    for (int i = tid; i < lim; i += 1024) {
        atomicAdd(&hcnt[dst[e0 + i] >> 9], 1);
    }
    __syncthreads();
    for (int b = tid; b < NBKT; b += 1024) {
        int c = hcnt[b];
        hbase[b] = c ? atomicAdd(&bktcur[b], c) : 0;
        hcnt[b] = 0;  // reuse as intra-block rank counter
    }
    __syncthreads();
    for (int i = tid; i < lim; i += 1024) {
        int d = dst[e0 + i];
        int s = src[e0 + i];
        int b = d >> 9;
        int r = atomicAdd(&hcnt[b], 1);
        binned[(size_t)b * BCAP + hbase[b] + r] = ((unsigned int)s << 9) | (d & 511);
    }
}

// ---------------- bucket base scan (196 values) ----------------

__global__ void k_bktscan(const int* __restrict__ bktcur, int* __restrict__ bktbase) {
    __shared__ int sa[256], sb[256];
    int t = threadIdx.x;
    int v = (t < NBKT) ? bktcur[t] : 0;
    sa[t] = v;
    __syncthreads();
    int* p = sa; int* q = sb;
    for (int off = 1; off < 256; off <<= 1) {
        q[t] = p[t] + ((t >= off) ? p[t - off] : 0);
        __syncthreads();
        int* tmp = p; p = q; q = tmp;
    }
    if (t < NBKT) bktbase[t] = p[t] - v;  // exclusive
}

// ---------------- pass C: per-bucket exact CSR + cnts + rowptr + dis ----------------

__global__ void k_build(const unsigned int* __restrict__ binned,
                        const int* __restrict__ bktcur, const int* __restrict__ bktbase,
                        int* __restrict__ csr, int* __restrict__ rowptr,
                        int* __restrict__ cnts, float* __restrict__ dis) {
    __shared__ int lcnt[512];
    __shared__ int lcur[512];
    __shared__ int sa[512], sb[512];
    int b = blockIdx.x;
    int tid = threadIdx.x;  // 256 threads
    int nbase = b << 9;
    int nnum = NN - nbase; if (nnum > 512) nnum = 512;
    int m = bktcur[b];
    int base = bktbase[b];
    const unsigned int* bp = binned + (size_t)b * BCAP;

    for (int n = tid; n < 512; n += 256) lcnt[n] = 0;
    __syncthreads();
    for (int i = tid; i < m; i += 256) atomicAdd(&lcnt[bp[i] & 511], 1);
    __syncthreads();
    for (int n = tid; n < 512; n += 256) sa[n] = lcnt[n];
    __syncthreads();
    int* p = sa; int* q = sb;
    for (int off = 1; off < 512; off <<= 1) {
        for (int n = tid; n < 512; n += 256)
            q[n] = p[n] + ((n >= off) ? p[n - off] : 0);
        __syncthreads();
        int* tmp = p; p = q; q = tmp;
    }
    for (int n = tid; n < 512; n += 256) {
        int pre = p[n] - lcnt[n];
        lcur[n] = pre;
        if (n < nnum) {
            int c = lcnt[n];
            rowptr[nbase + n] = base + pre;
            cnts[nbase + n] = c;
            dis[nbase + n] = rsqrtf((float)c + 1.0f);
        }
    }
    __syncthreads();
    for (int i = tid; i < m; i += 256) {
        unsigned int pk = bp[i];
        int ld = pk & 511;
        int s = (int)(pk >> 9);
        int r = atomicAdd(&lcur[ld], 1);
        csr[base + r] = s;
    }
}

// ---------------- layer 0: (A^ x) W0  — gather first on 8 channels ----------------

__global__ void k_prep_x(const float* __restrict__ x, const float* __restrict__ dis,
                         float* __restrict__ xp) {
    int t = blockIdx.x * blockDim.x + threadIdx.x;
    if (t < NN * 8) {
        int n = t >> 3, c = t & 7;
        xp[t] = (c < INC) ? dis[n] * x[n * INC + c] : 0.0f;
    }
}

__global__ void k_gather8(const float* __restrict__ xp, const int* __restrict__ csr,
                          const int* __restrict__ rowptr, const int* __restrict__ cnts,
                          const float* __restrict__ dis, float* __restrict__ aggx) {
    int t = blockIdx.x * blockDim.x + threadIdx.x;
    int d = t >> 3, c = t & 7;
    if (d >= NN) return;
    int beg = rowptr[d], num = cnts[d];
    float acc = xp[(size_t)d * 8 + c];
    int j = 0;
    while (j < num) {
        int chunk = min(num - j, 8);
        int iv = (c < chunk) ? csr[beg + j + c] : 0;
        for (int k = 0; k < chunk; ++k) {
            int s = __shfl(iv, k, 8);
            acc += xp[(size_t)s * 8 + c];
        }
        j += chunk;
    }
    aggx[(size_t)d * 8 + c] = dis[d] * acc;
}

// h0 = relu(aggx(:,0:7) @ W0 + b0) ; 16 nodes per block
__global__ void k_gemm8(const float* __restrict__ aggx, const float* __restrict__ W0,
                        const float* __restrict__ b0, float* __restrict__ h0) {
    __shared__ float sW[INC * HID];
    __shared__ float sx[16][8];
    int tid = threadIdx.x;
    for (int i = tid; i < INC * HID; i += 256) sW[i] = W0[i];
    int node0 = blockIdx.x * 16;
    if (tid < 128) {
        int n = node0 + (tid >> 3);
        sx[tid >> 3][tid & 7] = (n < NN) ? aggx[(size_t)n * 8 + (tid & 7)] : 0.0f;
    }
    __syncthreads();
    int c = tid & 63;
    float bias = b0[c];
#pragma unroll
    for (int sub = 0; sub < 4; ++sub) {
        int ns = sub * 4 + (tid >> 6);
        int n = node0 + ns;
        if (n < NN) {
            float acc = bias;
#pragma unroll
            for (int k = 0; k < INC; ++k) acc += sx[ns][k] * sW[k * HID + c];
            h0[(size_t)n * HID + c] = fmaxf(acc, 0.0f);
        }
    }
}

// ---------------- layer 1: register-blocked 64x64 GEMM (epilogue * dis) ----------------
// 256 threads = 16 node-quads x 16 ch-quads; 4x4 acc per thread.
// Per k: 1 ds_read_b128 (4 nodes, transposed tile) + 1 ds_read_b128 (4 ch of W) -> 16 FMA.

__global__ __launch_bounds__(256) void k_gemm_hid(const float* __restrict__ h,
                                                  const float* __restrict__ W,
                                                  const float* __restrict__ dis,
                                                  float* __restrict__ out) {
    __shared__ float sW[HID][HID];        // [k][c], 16 KB
    __shared__ float shT[HID][HID + 4];   // [k][n] transposed; +4 keeps rows 16B-aligned
    __shared__ float sdis[64];
    int tid = threadIdx.x;
    int n0 = blockIdx.x * 64;

    for (int i = tid; i < HID * HID; i += 256) sW[i >> 6][i & 63] = W[i];
    for (int i = tid; i < 64 * HID; i += 256) {
        int n = i >> 6, c = i & 63;
        int gn = n0 + n;
        shT[c][n] = (gn < NN) ? h[(size_t)gn * HID + c] : 0.0f;
    }
    if (tid < 64) sdis[tid] = (n0 + tid < NN) ? dis[n0 + tid] : 0.0f;
    __syncthreads();

    int tn = tid >> 4;  // node quad 0..15
    int tc = tid & 15;  // ch quad 0..15
    float acc[4][4] = {};
#pragma unroll 8
    for (int k = 0; k < HID; ++k) {
        float4 h4 = *(const float4*)&shT[k][tn * 4];
        float4 w4 = *(const float4*)&sW[k][tc * 4];
        float hv[4] = {h4.x, h4.y, h4.z, h4.w};
        float wv[4] = {w4.x, w4.y, w4.z, w4.w};
#pragma unroll
        for (int i = 0; i < 4; ++i)
#pragma unroll
            for (int j = 0; j < 4; ++j)
                acc[i][j] = fmaf(hv[i], wv[j], acc[i][j]);
    }
#pragma unroll
    for (int i = 0; i < 4; ++i) {
        int gn = n0 + tn * 4 + i;
        if (gn < NN) {
            float dsc = sdis[tn * 4 + i];
            float4 o = {dsc * acc[i][0], dsc * acc[i][1], dsc * acc[i][2], dsc * acc[i][3]};
            *(float4*)&out[(size_t)gn * HID + tc * 4] = o;
        }
    }
}

__global__ void k_gather64(const float* __restrict__ hwp, const int* __restrict__ csr,
                           const int* __restrict__ rowptr, const int* __restrict__ cnts,
                           const float* __restrict__ dis, const float* __restrict__ b,
                           float* __restrict__ out) {
    int t = blockIdx.x * blockDim.x + threadIdx.x;
    int d = t >> 6, c = t & 63;
    if (d >= NN) return;
    int beg = rowptr[d], num = cnts[d];
    float acc0 = hwp[(size_t)d * HID + c];
    float acc1 = 0.0f, acc2 = 0.0f, acc3 = 0.0f;
    int nv = (num < 64) ? num : 64;
    int iv = (c < nv) ? csr[beg + c] : 0;
    int j = 0;
    for (; j + 4 <= nv; j += 4) {
        int s0 = __shfl(iv, j);
        int s1 = __shfl(iv, j + 1);
        int s2 = __shfl(iv, j + 2);
        int s3 = __shfl(iv, j + 3);
        acc0 += hwp[(size_t)s0 * HID + c];
        acc1 += hwp[(size_t)s1 * HID + c];
        acc2 += hwp[(size_t)s2 * HID + c];
        acc3 += hwp[(size_t)s3 * HID + c];
    }
    for (; j < nv; ++j) {
        int s = __shfl(iv, j);
        acc0 += hwp[(size_t)s * HID + c];
    }
    for (; j < num; ++j) {
        int s = csr[beg + j];
        acc0 += hwp[(size_t)s * HID + c];
    }
    float v = dis[d] * ((acc0 + acc1) + (acc2 + acc3)) + b[c];
    out[t] = fmaxf(v, 0.0f);
}

// ---------------- layer 2 folded with head ----------------

__global__ void k_wc(const float* __restrict__ W2, const float* __restrict__ linW,
                     const float* __restrict__ b2, const float* __restrict__ linb,
                     float* __restrict__ Wc, float* __restrict__ bc) {
    int t = threadIdx.x;
    for (int i = t; i < HID * 16; i += 256) {
        int k = i >> 4, o = i & 15;
        float acc = 0.0f;
        if (o < OUTC)
            for (int q = 0; q < HID; ++q) acc += W2[k * HID + q] * linW[q * OUTC + o];
        Wc[i] = acc;
    }
    if (t < 16) {
        float acc = 0.0f;
        if (t < OUTC) {
            acc = linb[t];
            for (int q = 0; q < HID; ++q) acc += b2[q] * linW[q * OUTC + t];
        }
        bc[t] = acc;
    }
}

// z = dis ⊙ (h1 @ Wc)  [NN x 16]; register-blocked 64-node tile, acc[4] per thread
__global__ __launch_bounds__(256) void k_gemm_z(const float* __restrict__ h,
                                                const float* __restrict__ Wc,
                                                const float* __restrict__ dis,
                                                float* __restrict__ z) {
    __shared__ float sW[HID][16];         // [k][c], 4 KB
    __shared__ float shT[HID][HID + 4];   // [k][n] transposed
    __shared__ float sdis[64];
    int tid = threadIdx.x;
    int n0 = blockIdx.x * 64;

    for (int i = tid; i < HID * 16; i += 256) sW[i >> 4][i & 15] = Wc[i];
    for (int i = tid; i < 64 * HID; i += 256) {
        int n = i >> 6, c = i & 63;
        int gn = n0 + n;
        shT[c][n] = (gn < NN) ? h[(size_t)gn * HID + c] : 0.0f;
    }
    if (tid < 64) sdis[tid] = (n0 + tid < NN) ? dis[n0 + tid] : 0.0f;
    __syncthreads();

    int nq = tid >> 4;  // node quad 0..15
    int c  = tid & 15;  // channel 0..15
    float acc[4] = {};
#pragma unroll 8
    for (int k = 0; k < HID; ++k) {
        float4 h4 = *(const float4*)&shT[k][nq * 4];
        float w = sW[k][c];
        acc[0] = fmaf(h4.x, w, acc[0]);
        acc[1] = fmaf(h4.y, w, acc[1]);
        acc[2] = fmaf(h4.z, w, acc[2]);
        acc[3] = fmaf(h4.w, w, acc[3]);
    }
#pragma unroll
    for (int i = 0; i < 4; ++i) {
        int gn = n0 + nq * 4 + i;
        if (gn < NN) z[(size_t)gn * 16 + c] = sdis[nq * 4 + i] * acc[i];
    }
}

__global__ void k_gather16(const float* __restrict__ z, const int* __restrict__ csr,
                           const int* __restrict__ rowptr, const int* __restrict__ cnts,
                           const float* __restrict__ dis, float* __restrict__ agg2) {
    int t = blockIdx.x * blockDim.x + threadIdx.x;
    int d = t >> 4, c = t & 15;
    if (d >= NN) return;
    int beg = rowptr[d], num = cnts[d];
    float acc = z[(size_t)d * 16 + c];
    int j = 0;
    while (j < num) {
        int chunk = min(num - j, 16);
        int iv = (c < chunk) ? csr[beg + j + c] : 0;
        for (int k = 0; k < chunk; ++k) {
            int s = __shfl(iv, k, 16);
            acc += z[(size_t)s * 16 + c];
        }
        j += chunk;
    }
    agg2[(size_t)d * 16 + c] = dis[d] * acc;
}

// ---------------- pooling (16 ch) + head ----------------

#define PN 32
__global__ void k_pool16(const float* __restrict__ agg2, const int* __restrict__ batch,
                         float* __restrict__ sums, float* __restrict__ cnt) {
    int c = threadIdx.x & 15;
    int sub = threadIdx.x >> 4;
    int n0 = (blockIdx.x * 4 + sub) * PN;
    float acc = 0.0f, fc = 0.0f;
    int curg = -1;
    int nend = n0 + PN;
    if (nend > NN) nend = NN;
    for (int n = n0; n < nend; ++n) {
        int g = batch[n];
        if (g != curg) {
            if (curg >= 0) {
                atomicAdd(&sums[curg * 16 + c], acc);
                if (c == 0) atomicAdd(&cnt[curg], fc);
            }
            acc = 0.0f; fc = 0.0f; curg = g;
        }
        acc += agg2[(size_t)n * 16 + c];
        fc += 1.0f;
    }
    if (curg >= 0) {
        atomicAdd(&sums[curg * 16 + c], acc);
        if (c == 0) atomicAdd(&cnt[curg], fc);
    }
}

__global__ void k_final2(const float* __restrict__ sums, const float* __restrict__ cnt,
                         const float* __restrict__ bc, float* __restrict__ out) {
    int t = blockIdx.x * blockDim.x + threadIdx.x;
    if (t < NG * OUTC) {
        int g = t / OUTC, o = t % OUTC;
        out[t] = sums[g * 16 + o] / fmaxf(cnt[g], 1.0f) + bc[o];
    }
}

// ---------------- launch ----------------

extern "C" void kernel_launch(void* const* d_in, const int* in_sizes, int n_in,
                              void* d_out, int out_size, void* d_ws, size_t ws_size,
                              hipStream_t stream) {
    const float* x     = (const float*)d_in[0];
    const int*   ei    = (const int*)d_in[1];  // [2, NE]
    const int*   src   = ei;
    const int*   dst   = ei + NE;
    const int*   batch = (const int*)d_in[2];
    const float* W0 = (const float*)d_in[3];
    const float* b0 = (const float*)d_in[4];
    const float* W1 = (const float*)d_in[5];
    const float* b1 = (const float*)d_in[6];
    const float* W2 = (const float*)d_in[7];
    const float* b2 = (const float*)d_in[8];
    const float* linW = (const float*)d_in[9];
    const float* linb = (const float*)d_in[10];
    float* out = (float*)d_out;

    char* ws = (char*)d_ws;
    float* bufA    = (float*)ws;               ws += sizeof(float) * NN * HID;
    float* bufB    = (float*)ws;               ws += sizeof(float) * NN * HID;
    float* dis     = (float*)ws;               ws += sizeof(float) * NN;
    float* sums    = (float*)ws;               ws += sizeof(float) * NG * 16;
    float* cnt     = (float*)ws;               ws += sizeof(float) * NG;
    float* Wc      = (float*)ws;               ws += sizeof(float) * HID * 16;
    float* bc      = (float*)ws;               ws += sizeof(float) * 16;
    int*   cnts    = (int*)ws;                 ws += sizeof(int) * NN;
    int*   rowptr  = (int*)ws;                 ws += sizeof(int) * NN;
    int*   bktcur  = (int*)ws;                 ws += sizeof(int) * NBKT;
    int*   bktbase = (int*)ws;                 ws += sizeof(int) * NBKT;
    int*   csr     = (int*)ws;                 ws += sizeof(int) * NE;

    // aliases (lifetimes disjoint):
    unsigned int* binned = (unsigned int*)bufA;  // 6.4 MB, dead before prep_x
    float* xp   = bufA;               // [NN*8]
    float* aggx = bufA + NN * 8;      // [NN*8]
    float* h0   = bufB;               // [NN*64]
    float* hwp  = bufA;               // [NN*64]
    float* h1   = bufB;               // [NN*64]
    float* zz   = bufA;               // [NN*16]
    float* agg2 = bufB;               // [NN*16]

    const int TB = 256;

    // ---- CSR + normalization build (counting sort, dense writes) ----
    k_zero<<<16, TB, 0, stream>>>(sums, cnt, bktcur);
    k_bin<<<NBIN_BLK, 1024, 0, stream>>>(src, dst, bktcur, binned);
    k_bktscan<<<1, TB, 0, stream>>>(bktcur, bktbase);
    k_build<<<NBKT, TB, 0, stream>>>(binned, bktcur, bktbase, csr, rowptr, cnts, dis);

    // ---- layer 0: gather(8ch) then transform ----
    k_prep_x<<<(NN * 8 + TB - 1) / TB, TB, 0, stream>>>(x, dis, xp);
    k_gather8<<<(NN * 8 + TB - 1) / TB, TB, 0, stream>>>(xp, csr, rowptr, cnts, dis, aggx);
    k_gemm8<<<(NN + 15) / 16, TB, 0, stream>>>(aggx, W0, b0, h0);

    // ---- layer 1: transform then gather(64ch) ----
    k_gemm_hid<<<(NN + 63) / 64, TB, 0, stream>>>(h0, W1, dis, hwp);
    k_gather64<<<(NN * HID + TB - 1) / TB, TB, 0, stream>>>(hwp, csr, rowptr, cnts, dis, b1, h1);

    // ---- layer 2 folded with linear head: 16-ch pipeline ----
    k_wc<<<1, TB, 0, stream>>>(W2, linW, b2, linb, Wc, bc);
    k_gemm_z<<<(NN + 63) / 64, TB, 0, stream>>>(h1, Wc, dis, zz);
    k_gather16<<<(NN * 16 + TB - 1) / TB, TB, 0, stream>>>(zz, csr, rowptr, cnts, dis, agg2);

    // ---- pool + head ----
    k_pool16<<<(NN + 4 * PN - 1) / (4 * PN), 64, 0, stream>>>(agg2, batch, sums, cnt);
    k_final2<<<(NG * OUTC + TB - 1) / TB, TB, 0, stream>>>(sums, cnt, bc, out);
}

// Round 7
// 276.499 us; speedup vs baseline: 4.0724x; 1.0967x over previous
//
#include <hip/hip_runtime.h>

#define NN 100000
#define NE 1200000
#define NG 256
#define INC 7
#define HID 64
#define OUTC 10

#define NBKT 196          // ceil(NN / 512) buckets of 512 nodes
#define BCAP 8192         // per-bucket capacity (avg 6144)
#define BIN_CHUNK 16384   // edges per k_bin block
#define NBIN_BLK ((NE + BIN_CHUNK - 1) / BIN_CHUNK)  // 74
#define EPT (BIN_CHUNK / 1024)  // 16 edges per thread in k_bin

// ---------------- zero init (ws is poisoned 0xAA before every call) ----------------

__global__ void k_zero(float* __restrict__ sums, float* __restrict__ cnt,
                       int* __restrict__ bktcur) {
    int i = blockIdx.x * blockDim.x + threadIdx.x;
    if (i < NG * 16) sums[i] = 0.0f;
    if (i < NG) cnt[i] = 0.0f;
    if (i < NBKT) bktcur[i] = 0;
}

// ---------------- pass B: bin edges by dst>>9, packed (src<<9)|(dst&511) ----------------

__global__ __launch_bounds__(1024) void k_bin(const int* __restrict__ src,
                                              const int* __restrict__ dst,
                                              int* __restrict__ bktcur,
                                              unsigned int* __restrict__ binned) {
    __shared__ int hcnt[NBKT];
    __shared__ int hbase[NBKT];
    int tid = threadIdx.x;
    int e0 = blockIdx.x * BIN_CHUNK;
    int lim = NE - e0; if (lim > BIN_CHUNK) lim = BIN_CHUNK;

    int dr[EPT], sr[EPT];  // register-cached edges (strided)
    for (int b = tid; b < NBKT; b += 1024) hcnt[b] = 0;
    __syncthreads();
#pragma unroll
    for (int u = 0; u < EPT; ++u) {
        int i = tid + u * 1024;
        bool ok = i < lim;
        dr[u] = ok ? dst[e0 + i] : -1;
        sr[u] = ok ? src[e0 + i] : 0;
        if (ok) atomicAdd(&hcnt[dr[u] >> 9], 1);
    }
    __syncthreads();
    for (int b = tid; b < NBKT; b += 1024) {
        int c = hcnt[b];
        hbase[b] = c ? atomicAdd(&bktcur[b], c) : 0;
        hcnt[b] = 0;  // reuse as intra-block rank counter
    }
    __syncthreads();
#pragma unroll
    for (int u = 0; u < EPT; ++u) {
        if (dr[u] >= 0) {
            int b = dr[u] >> 9;
            int r = atomicAdd(&hcnt[b], 1);
            binned[(size_t)b * BCAP + hbase[b] + r] =
                ((unsigned int)sr[u] << 9) | (dr[u] & 511);
        }
    }
}

// ---------------- bucket base scan (196 values) ----------------

__global__ void k_bktscan(const int* __restrict__ bktcur, int* __restrict__ bktbase) {
    __shared__ int sa[256], sb[256];
    int t = threadIdx.x;
    int v = (t < NBKT) ? bktcur[t] : 0;
    sa[t] = v;
    __syncthreads();
    int* p = sa; int* q = sb;
    for (int off = 1; off < 256; off <<= 1) {
        q[t] = p[t] + ((t >= off) ? p[t - off] : 0);
        __syncthreads();
        int* tmp = p; p = q; q = tmp;
    }
    if (t < NBKT) bktbase[t] = p[t] - v;  // exclusive
}

// ---------------- pass C: per-bucket exact CSR + cnts + rowptr + dis ----------------

__global__ void k_build(const unsigned int* __restrict__ binned,
                        const int* __restrict__ bktcur, const int* __restrict__ bktbase,
                        int* __restrict__ csr, int* __restrict__ rowptr,
                        int* __restrict__ cnts, float* __restrict__ dis) {
    __shared__ int lcnt[512];
    __shared__ int lcur[512];
    __shared__ int sa[512], sb[512];
    int b = blockIdx.x;
    int tid = threadIdx.x;  // 256 threads
    int nbase = b << 9;
    int nnum = NN - nbase; if (nnum > 512) nnum = 512;
    int m = bktcur[b];
    int base = bktbase[b];
    const unsigned int* bp = binned + (size_t)b * BCAP;

    for (int n = tid; n < 512; n += 256) lcnt[n] = 0;
    __syncthreads();
    for (int i = tid; i < m; i += 256) atomicAdd(&lcnt[bp[i] & 511], 1);
    __syncthreads();
    for (int n = tid; n < 512; n += 256) sa[n] = lcnt[n];
    __syncthreads();
    int* p = sa; int* q = sb;
    for (int off = 1; off < 512; off <<= 1) {
        for (int n = tid; n < 512; n += 256)
            q[n] = p[n] + ((n >= off) ? p[n - off] : 0);
        __syncthreads();
        int* tmp = p; p = q; q = tmp;
    }
    for (int n = tid; n < 512; n += 256) {
        int pre = p[n] - lcnt[n];
        lcur[n] = pre;
        if (n < nnum) {
            int c = lcnt[n];
            rowptr[nbase + n] = base + pre;
            cnts[nbase + n] = c;
            dis[nbase + n] = rsqrtf((float)c + 1.0f);
        }
    }
    __syncthreads();
    for (int i = tid; i < m; i += 256) {
        unsigned int pk = bp[i];
        int ld = pk & 511;
        int s = (int)(pk >> 9);
        int r = atomicAdd(&lcur[ld], 1);
        csr[base + r] = s;
    }
}

// ---------------- layer 0: (A^ x) W0  — gather first on 8 channels ----------------

__global__ void k_prep_x(const float* __restrict__ x, const float* __restrict__ dis,
                         float* __restrict__ xp) {
    int t = blockIdx.x * blockDim.x + threadIdx.x;
    if (t < NN * 8) {
        int n = t >> 3, c = t & 7;
        xp[t] = (c < INC) ? dis[n] * x[n * INC + c] : 0.0f;
    }
}

// 4 lanes x float2 per dst; 16 dsts per wave
__global__ void k_gather8(const float* __restrict__ xp, const int* __restrict__ csr,
                          const int* __restrict__ rowptr, const int* __restrict__ cnts,
                          const float* __restrict__ dis, float* __restrict__ aggx) {
    int t = blockIdx.x * blockDim.x + threadIdx.x;
    int d = t >> 2, l = t & 3;
    if (d >= NN) return;
    int beg = rowptr[d], num = cnts[d];
    float2 a0 = ((const float2*)&xp[(size_t)d * 8])[l];
    float2 a1 = {0.0f, 0.0f};
    int j = 0;
    while (j < num) {
        int chunk = min(num - j, 4);
        int iv = (l < chunk) ? csr[beg + j + l] : 0;
        int k = 0;
        for (; k + 2 <= chunk; k += 2) {
            int s0 = __shfl(iv, k, 4);
            int s1 = __shfl(iv, k + 1, 4);
            float2 r0 = ((const float2*)&xp[(size_t)s0 * 8])[l];
            float2 r1 = ((const float2*)&xp[(size_t)s1 * 8])[l];
            a0.x += r0.x; a0.y += r0.y;
            a1.x += r1.x; a1.y += r1.y;
        }
        for (; k < chunk; ++k) {
            int s = __shfl(iv, k, 4);
            float2 r = ((const float2*)&xp[(size_t)s * 8])[l];
            a0.x += r.x; a0.y += r.y;
        }
        j += chunk;
    }
    float dd = dis[d];
    float2 v = {dd * (a0.x + a1.x), dd * (a0.y + a1.y)};
    ((float2*)&aggx[(size_t)d * 8])[l] = v;
}

// h0 = relu(aggx(:,0:7) @ W0 + b0) ; 16 nodes per block
__global__ void k_gemm8(const float* __restrict__ aggx, const float* __restrict__ W0,
                        const float* __restrict__ b0, float* __restrict__ h0) {
    __shared__ float sW[INC * HID];
    __shared__ float sx[16][8];
    int tid = threadIdx.x;
    for (int i = tid; i < INC * HID; i += 256) sW[i] = W0[i];
    int node0 = blockIdx.x * 16;
    if (tid < 128) {
        int n = node0 + (tid >> 3);
        sx[tid >> 3][tid & 7] = (n < NN) ? aggx[(size_t)n * 8 + (tid & 7)] : 0.0f;
    }
    __syncthreads();
    int c = tid & 63;
    float bias = b0[c];
#pragma unroll
    for (int sub = 0; sub < 4; ++sub) {
        int ns = sub * 4 + (tid >> 6);
        int n = node0 + ns;
        if (n < NN) {
            float acc = bias;
#pragma unroll
            for (int k = 0; k < INC; ++k) acc += sx[ns][k] * sW[k * HID + c];
            h0[(size_t)n * HID + c] = fmaxf(acc, 0.0f);
        }
    }
}

// ---------------- layer 1: register-blocked 64x64 GEMM (epilogue * dis) ----------------

__global__ __launch_bounds__(256) void k_gemm_hid(const float* __restrict__ h,
                                                  const float* __restrict__ W,
                                                  const float* __restrict__ dis,
                                                  float* __restrict__ out) {
    __shared__ float sW[HID][HID];        // [k][c], 16 KB
    __shared__ float shT[HID][HID + 4];   // [k][n] transposed; +4 keeps rows 16B-aligned
    __shared__ float sdis[64];
    int tid = threadIdx.x;
    int n0 = blockIdx.x * 64;

    for (int i = tid; i < HID * HID; i += 256) sW[i >> 6][i & 63] = W[i];
    for (int i = tid; i < 64 * HID; i += 256) {
        int n = i >> 6, c = i & 63;
        int gn = n0 + n;
        shT[c][n] = (gn < NN) ? h[(size_t)gn * HID + c] : 0.0f;
    }
    if (tid < 64) sdis[tid] = (n0 + tid < NN) ? dis[n0 + tid] : 0.0f;
    __syncthreads();

    int tn = tid >> 4;  // node quad 0..15
    int tc = tid & 15;  // ch quad 0..15
    float acc[4][4] = {};
#pragma unroll 8
    for (int k = 0; k < HID; ++k) {
        float4 h4 = *(const float4*)&shT[k][tn * 4];
        float4 w4 = *(const float4*)&sW[k][tc * 4];
        float hv[4] = {h4.x, h4.y, h4.z, h4.w};
        float wv[4] = {w4.x, w4.y, w4.z, w4.w};
#pragma unroll
        for (int i = 0; i < 4; ++i)
#pragma unroll
            for (int j = 0; j < 4; ++j)
                acc[i][j] = fmaf(hv[i], wv[j], acc[i][j]);
    }
#pragma unroll
    for (int i = 0; i < 4; ++i) {
        int gn = n0 + tn * 4 + i;
        if (gn < NN) {
            float dsc = sdis[tn * 4 + i];
            float4 o = {dsc * acc[i][0], dsc * acc[i][1], dsc * acc[i][2], dsc * acc[i][3]};
            *(float4*)&out[(size_t)gn * HID + tc * 4] = o;
        }
    }
}

// 16 lanes x float4 per dst; 4 dsts per wave; 4-deep MLP unroll
__global__ void k_gather64(const float* __restrict__ hwp, const int* __restrict__ csr,
                           const int* __restrict__ rowptr, const int* __restrict__ cnts,
                           const float* __restrict__ dis, const float* __restrict__ b,
                           float* __restrict__ out) {
    int t = blockIdx.x * blockDim.x + threadIdx.x;
    int d = t >> 4, l = t & 15;
    if (d >= NN) return;
    int beg = rowptr[d], num = cnts[d];
    float4 a0 = ((const float4*)&hwp[(size_t)d * HID])[l];
    float4 a1 = {0.f, 0.f, 0.f, 0.f};
    float4 a2 = {0.f, 0.f, 0.f, 0.f};
    float4 a3 = {0.f, 0.f, 0.f, 0.f};
    int j = 0;
    while (j < num) {
        int chunk = min(num - j, 16);
        int iv = (l < chunk) ? csr[beg + j + l] : 0;
        int k = 0;
        for (; k + 4 <= chunk; k += 4) {
            int s0 = __shfl(iv, k, 16);
            int s1 = __shfl(iv, k + 1, 16);
            int s2 = __shfl(iv, k + 2, 16);
            int s3 = __shfl(iv, k + 3, 16);
            float4 r0 = ((const float4*)&hwp[(size_t)s0 * HID])[l];
            float4 r1 = ((const float4*)&hwp[(size_t)s1 * HID])[l];
            float4 r2 = ((const float4*)&hwp[(size_t)s2 * HID])[l];
            float4 r3 = ((const float4*)&hwp[(size_t)s3 * HID])[l];
            a0.x += r0.x; a0.y += r0.y; a0.z += r0.z; a0.w += r0.w;
            a1.x += r1.x; a1.y += r1.y; a1.z += r1.z; a1.w += r1.w;
            a2.x += r2.x; a2.y += r2.y; a2.z += r2.z; a2.w += r2.w;
            a3.x += r3.x; a3.y += r3.y; a3.z += r3.z; a3.w += r3.w;
        }
        for (; k < chunk; ++k) {
            int s = __shfl(iv, k, 16);
            float4 r = ((const float4*)&hwp[(size_t)s * HID])[l];
            a0.x += r.x; a0.y += r.y; a0.z += r.z; a0.w += r.w;
        }
        j += chunk;
    }
    float dd = dis[d];
    float4 bias = ((const float4*)b)[l];
    float4 v;
    v.x = fmaxf(dd * ((a0.x + a1.x) + (a2.x + a3.x)) + bias.x, 0.0f);
    v.y = fmaxf(dd * ((a0.y + a1.y) + (a2.y + a3.y)) + bias.y, 0.0f);
    v.z = fmaxf(dd * ((a0.z + a1.z) + (a2.z + a3.z)) + bias.z, 0.0f);
    v.w = fmaxf(dd * ((a0.w + a1.w) + (a2.w + a3.w)) + bias.w, 0.0f);
    ((float4*)&out[(size_t)d * HID])[l] = v;
}

// ---------------- layer 2 folded with head ----------------

__global__ void k_wc(const float* __restrict__ W2, const float* __restrict__ linW,
                     const float* __restrict__ b2, const float* __restrict__ linb,
                     float* __restrict__ Wc, float* __restrict__ bc) {
    int t = threadIdx.x;
    for (int i = t; i < HID * 16; i += 256) {
        int k = i >> 4, o = i & 15;
        float acc = 0.0f;
        if (o < OUTC)
            for (int q = 0; q < HID; ++q) acc += W2[k * HID + q] * linW[q * OUTC + o];
        Wc[i] = acc;
    }
    if (t < 16) {
        float acc = 0.0f;
        if (t < OUTC) {
            acc = linb[t];
            for (int q = 0; q < HID; ++q) acc += b2[q] * linW[q * OUTC + t];
        }
        bc[t] = acc;
    }
}

// z = dis ⊙ (h1 @ Wc)  [NN x 16]; register-blocked 64-node tile, acc[4] per thread
__global__ __launch_bounds__(256) void k_gemm_z(const float* __restrict__ h,
                                                const float* __restrict__ Wc,
                                                const float* __restrict__ dis,
                                                float* __restrict__ z) {
    __shared__ float sW[HID][16];         // [k][c], 4 KB
    __shared__ float shT[HID][HID + 4];   // [k][n] transposed
    __shared__ float sdis[64];
    int tid = threadIdx.x;
    int n0 = blockIdx.x * 64;

    for (int i = tid; i < HID * 16; i += 256) sW[i >> 4][i & 15] = Wc[i];
    for (int i = tid; i < 64 * HID; i += 256) {
        int n = i >> 6, c = i & 63;
        int gn = n0 + n;
        shT[c][n] = (gn < NN) ? h[(size_t)gn * HID + c] : 0.0f;
    }
    if (tid < 64) sdis[tid] = (n0 + tid < NN) ? dis[n0 + tid] : 0.0f;
    __syncthreads();

    int nq = tid >> 4;  // node quad 0..15
    int c  = tid & 15;  // channel 0..15
    float acc[4] = {};
#pragma unroll 8
    for (int k = 0; k < HID; ++k) {
        float4 h4 = *(const float4*)&shT[k][nq * 4];
        float w = sW[k][c];
        acc[0] = fmaf(h4.x, w, acc[0]);
        acc[1] = fmaf(h4.y, w, acc[1]);
        acc[2] = fmaf(h4.z, w, acc[2]);
        acc[3] = fmaf(h4.w, w, acc[3]);
    }
#pragma unroll
    for (int i = 0; i < 4; ++i) {
        int gn = n0 + nq * 4 + i;
        if (gn < NN) z[(size_t)gn * 16 + c] = sdis[nq * 4 + i] * acc[i];
    }
}

// 4 lanes x float4 per dst; 16 dsts per wave
__global__ void k_gather16(const float* __restrict__ z, const int* __restrict__ csr,
                           const int* __restrict__ rowptr, const int* __restrict__ cnts,
                           const float* __restrict__ dis, float* __restrict__ agg2) {
    int t = blockIdx.x * blockDim.x + threadIdx.x;
    int d = t >> 2, l = t & 3;
    if (d >= NN) return;
    int beg = rowptr[d], num = cnts[d];
    float4 a0 = ((const float4*)&z[(size_t)d * 16])[l];
    float4 a1 = {0.f, 0.f, 0.f, 0.f};
    int j = 0;
    while (j < num) {
        int chunk = min(num - j, 4);
        int iv = (l < chunk) ? csr[beg + j + l] : 0;
        int k = 0;
        for (; k + 2 <= chunk; k += 2) {
            int s0 = __shfl(iv, k, 4);
            int s1 = __shfl(iv, k + 1, 4);
            float4 r0 = ((const float4*)&z[(size_t)s0 * 16])[l];
            float4 r1 = ((const float4*)&z[(size_t)s1 * 16])[l];
            a0.x += r0.x; a0.y += r0.y; a0.z += r0.z; a0.w += r0.w;
            a1.x += r1.x; a1.y += r1.y; a1.z += r1.z; a1.w += r1.w;
        }
        for (; k < chunk; ++k) {
            int s = __shfl(iv, k, 4);
            float4 r = ((const float4*)&z[(size_t)s * 16])[l];
            a0.x += r.x; a0.y += r.y; a0.z += r.z; a0.w += r.w;
        }
        j += chunk;
    }
    float dd = dis[d];
    float4 v = {dd * (a0.x + a1.x), dd * (a0.y + a1.y),
                dd * (a0.z + a1.z), dd * (a0.w + a1.w)};
    ((float4*)&agg2[(size_t)d * 16])[l] = v;
}

// ---------------- pooling (16 ch) + head ----------------

#define PN 32
__global__ void k_pool16(const float* __restrict__ agg2, const int* __restrict__ batch,
                         float* __restrict__ sums, float* __restrict__ cnt) {
    int c = threadIdx.x & 15;
    int sub = threadIdx.x >> 4;
    int n0 = (blockIdx.x * 4 + sub) * PN;
    float acc = 0.0f, fc = 0.0f;
    int curg = -1;
    int nend = n0 + PN;
    if (nend > NN) nend = NN;
    for (int n = n0; n < nend; ++n) {
        int g = batch[n];
        if (g != curg) {
            if (curg >= 0) {
                atomicAdd(&sums[curg * 16 + c], acc);
                if (c == 0) atomicAdd(&cnt[curg], fc);
            }
            acc = 0.0f; fc = 0.0f; curg = g;
        }
        acc += agg2[(size_t)n * 16 + c];
        fc += 1.0f;
    }
    if (curg >= 0) {
        atomicAdd(&sums[curg * 16 + c], acc);
        if (c == 0) atomicAdd(&cnt[curg], fc);
    }
}

__global__ void k_final2(const float* __restrict__ sums, const float* __restrict__ cnt,
                         const float* __restrict__ bc, float* __restrict__ out) {
    int t = blockIdx.x * blockDim.x + threadIdx.x;
    if (t < NG * OUTC) {
        int g = t / OUTC, o = t % OUTC;
        out[t] = sums[g * 16 + o] / fmaxf(cnt[g], 1.0f) + bc[o];
    }
}

// ---------------- launch ----------------

extern "C" void kernel_launch(void* const* d_in, const int* in_sizes, int n_in,
                              void* d_out, int out_size, void* d_ws, size_t ws_size,
                              hipStream_t stream) {
    const float* x     = (const float*)d_in[0];
    const int*   ei    = (const int*)d_in[1];  // [2, NE]
    const int*   src   = ei;
    const int*   dst   = ei + NE;
    const int*   batch = (const int*)d_in[2];
    const float* W0 = (const float*)d_in[3];
    const float* b0 = (const float*)d_in[4];
    const float* W1 = (const float*)d_in[5];
    const float* b1 = (const float*)d_in[6];
    const float* W2 = (const float*)d_in[7];
    const float* b2 = (const float*)d_in[8];
    const float* linW = (const float*)d_in[9];
    const float* linb = (const float*)d_in[10];
    float* out = (float*)d_out;

    char* ws = (char*)d_ws;
    float* bufA    = (float*)ws;               ws += sizeof(float) * NN * HID;
    float* bufB    = (float*)ws;               ws += sizeof(float) * NN * HID;
    float* dis     = (float*)ws;               ws += sizeof(float) * NN;
    float* sums    = (float*)ws;               ws += sizeof(float) * NG * 16;
    float* cnt     = (float*)ws;               ws += sizeof(float) * NG;
    float* Wc      = (float*)ws;               ws += sizeof(float) * HID * 16;
    float* bc      = (float*)ws;               ws += sizeof(float) * 16;
    int*   cnts    = (int*)ws;                 ws += sizeof(int) * NN;
    int*   rowptr  = (int*)ws;                 ws += sizeof(int) * NN;
    int*   bktcur  = (int*)ws;                 ws += sizeof(int) * NBKT;
    int*   bktbase = (int*)ws;                 ws += sizeof(int) * NBKT;
    int*   csr     = (int*)ws;                 ws += sizeof(int) * NE;

    // aliases (lifetimes disjoint):
    unsigned int* binned = (unsigned int*)bufA;  // 6.4 MB, dead before prep_x
    float* xp   = bufA;               // [NN*8]
    float* aggx = bufA + NN * 8;      // [NN*8]
    float* h0   = bufB;               // [NN*64]
    float* hwp  = bufA;               // [NN*64]
    float* h1   = bufB;               // [NN*64]
    float* zz   = bufA;               // [NN*16]
    float* agg2 = bufB;               // [NN*16]

    const int TB = 256;

    // ---- CSR + normalization build (counting sort, dense writes) ----
    k_zero<<<16, TB, 0, stream>>>(sums, cnt, bktcur);
    k_bin<<<NBIN_BLK, 1024, 0, stream>>>(src, dst, bktcur, binned);
    k_bktscan<<<1, TB, 0, stream>>>(bktcur, bktbase);
    k_build<<<NBKT, TB, 0, stream>>>(binned, bktcur, bktbase, csr, rowptr, cnts, dis);

    // ---- layer 0: gather(8ch) then transform ----
    k_prep_x<<<(NN * 8 + TB - 1) / TB, TB, 0, stream>>>(x, dis, xp);
    k_gather8<<<(NN * 4 + TB - 1) / TB, TB, 0, stream>>>(xp, csr, rowptr, cnts, dis, aggx);
    k_gemm8<<<(NN + 15) / 16, TB, 0, stream>>>(aggx, W0, b0, h0);

    // ---- layer 1: transform then gather(64ch) ----
    k_gemm_hid<<<(NN + 63) / 64, TB, 0, stream>>>(h0, W1, dis, hwp);
    k_gather64<<<(NN * 16 + TB - 1) / TB, TB, 0, stream>>>(hwp, csr, rowptr, cnts, dis, b1, h1);

    // ---- layer 2 folded with linear head: 16-ch pipeline ----
    k_wc<<<1, TB, 0, stream>>>(W2, linW, b2, linb, Wc, bc);
    k_gemm_z<<<(NN + 63) / 64, TB, 0, stream>>>(h1, Wc, dis, zz);
    k_gather16<<<(NN * 4 + TB - 1) / TB, TB, 0, stream>>>(zz, csr, rowptr, cnts, dis, agg2);

    // ---- pool + head ----
    k_pool16<<<(NN + 4 * PN - 1) / (4 * PN), 64, 0, stream>>>(agg2, batch, sums, cnt);
    k_final2<<<(NG * OUTC + TB - 1) / TB, TB, 0, stream>>>(sums, cnt, bc, out);
}

// Round 8
// 224.435 us; speedup vs baseline: 5.0171x; 1.2320x over previous
//
#include <hip/hip_runtime.h>

#define NN 100000
#define NE 1200000
#define NG 256
#define INC 7
#define HID 64
#define OUTC 10

#define NBKT 196          // ceil(NN / 512) buckets of 512 nodes
#define BCAP 8192         // per-bucket capacity (avg 6144)
#define BIN_CHUNK 4096    // edges per k_bin block (256 thr)
#define NBIN_BLK ((NE + BIN_CHUNK - 1) / BIN_CHUNK)  // 293
#define EPT (BIN_CHUNK / 256)  // 16 edges per thread
#define NBLK64 ((NN + 63) / 64)  // 1563

typedef unsigned int uint;
typedef unsigned short ushort;

// ---- bf16 helpers (RNE) ----
__device__ inline uint pk2bf(float a, float b) {
    uint ua = __float_as_uint(a);
    ua = (ua + 0x7fffu + ((ua >> 16) & 1u)) >> 16;
    uint ub = __float_as_uint(b);
    ub = (ub + 0x7fffu + ((ub >> 16) & 1u)) & 0xffff0000u;
    return ua | ub;
}
__device__ inline ushort f2bf(float f) {
    uint u = __float_as_uint(f);
    return (ushort)((u + 0x7fffu + ((u >> 16) & 1u)) >> 16);
}
__device__ inline void acc8(float* a, uint4 r) {
    a[0] += __uint_as_float(r.x << 16); a[1] += __uint_as_float(r.x & 0xffff0000u);
    a[2] += __uint_as_float(r.y << 16); a[3] += __uint_as_float(r.y & 0xffff0000u);
    a[4] += __uint_as_float(r.z << 16); a[5] += __uint_as_float(r.z & 0xffff0000u);
    a[6] += __uint_as_float(r.w << 16); a[7] += __uint_as_float(r.w & 0xffff0000u);
}
__device__ inline float4 cvt4(uint2 r) {
    float4 f;
    f.x = __uint_as_float(r.x << 16); f.y = __uint_as_float(r.x & 0xffff0000u);
    f.z = __uint_as_float(r.y << 16); f.w = __uint_as_float(r.y & 0xffff0000u);
    return f;
}

// ---------------- K1: zero init ----------------

__global__ void k_zero(float* __restrict__ sums, float* __restrict__ cnt,
                       int* __restrict__ bktcur) {
    int i = blockIdx.x * blockDim.x + threadIdx.x;
    if (i < NG * 16) sums[i] = 0.0f;
    if (i < NG) cnt[i] = 0.0f;
    if (i < NBKT) bktcur[i] = 0;
}

// ---------------- K2: bin edges by dst>>9, packed (src<<9)|(dst&511) ----------------

__global__ __launch_bounds__(256) void k_bin(const int* __restrict__ src,
                                             const int* __restrict__ dst,
                                             int* __restrict__ bktcur,
                                             uint* __restrict__ binned) {
    __shared__ int hcnt[NBKT];
    __shared__ int hbase[NBKT];
    int tid = threadIdx.x;
    int e0 = blockIdx.x * BIN_CHUNK;
    int lim = NE - e0; if (lim > BIN_CHUNK) lim = BIN_CHUNK;

    int dr[EPT], sr[EPT];
    for (int b = tid; b < NBKT; b += 256) hcnt[b] = 0;
    __syncthreads();
#pragma unroll
    for (int u = 0; u < EPT; ++u) {
        int i = tid + u * 256;
        bool ok = i < lim;
        dr[u] = ok ? dst[e0 + i] : -1;
        sr[u] = ok ? src[e0 + i] : 0;
        if (ok) atomicAdd(&hcnt[dr[u] >> 9], 1);
    }
    __syncthreads();
    for (int b = tid; b < NBKT; b += 256) {
        int c = hcnt[b];
        hbase[b] = c ? atomicAdd(&bktcur[b], c) : 0;
        hcnt[b] = 0;  // reuse as intra-block rank counter
    }
    __syncthreads();
#pragma unroll
    for (int u = 0; u < EPT; ++u) {
        if (dr[u] >= 0) {
            int b = dr[u] >> 9;
            int r = atomicAdd(&hcnt[b], 1);
            binned[(size_t)b * BCAP + hbase[b] + r] = ((uint)sr[u] << 9) | (dr[u] & 511);
        }
    }
}

// ---------------- K3: per-bucket CSR + cnts + rowptr + dis + prep_x ----------------
// (folds the bucket-base scan and the layer-0 input prescale into the same kernel)

__global__ __launch_bounds__(256) void k_build(const uint* __restrict__ binned,
                                               const int* __restrict__ bktcur,
                                               int* __restrict__ csr,
                                               int* __restrict__ rowptr,
                                               int* __restrict__ cnts,
                                               float* __restrict__ dis,
                                               const float* __restrict__ x,
                                               float* __restrict__ xp) {
    __shared__ int lcnt[512];
    __shared__ int lcur[512];
    __shared__ int sa[512], sb[512];
    __shared__ int s_base, s_m;
    int b = blockIdx.x;
    int tid = threadIdx.x;  // 256 threads
    int nbase = b << 9;
    int nnum = NN - nbase; if (nnum > 512) nnum = 512;

    // bucket-base: scan the 196 bucket sizes in-block
    {
        int v = (tid < NBKT) ? bktcur[tid] : 0;
        sa[tid] = v;
        __syncthreads();
        int* p = sa; int* q = sb;
        for (int off = 1; off < 256; off <<= 1) {
            q[tid] = p[tid] + ((tid >= off) ? p[tid - off] : 0);
            __syncthreads();
            int* t2 = p; p = q; q = t2;
        }
        if (tid == b) { s_base = p[tid] - v; s_m = v; }
        __syncthreads();
    }
    int m = s_m;
    int base = s_base;
    const uint* bp = binned + (size_t)b * BCAP;

    for (int n = tid; n < 512; n += 256) lcnt[n] = 0;
    __syncthreads();
    for (int i = tid; i < m; i += 256) atomicAdd(&lcnt[bp[i] & 511], 1);
    __syncthreads();
    for (int n = tid; n < 512; n += 256) sa[n] = lcnt[n];
    __syncthreads();
    int* p = sa; int* q = sb;
    for (int off = 1; off < 512; off <<= 1) {
        for (int n = tid; n < 512; n += 256)
            q[n] = p[n] + ((n >= off) ? p[n - off] : 0);
        __syncthreads();
        int* t2 = p; p = q; q = t2;
    }
    for (int n = tid; n < 512; n += 256) {
        int pre = p[n] - lcnt[n];
        lcur[n] = pre;
        if (n < nnum) {
            int c = lcnt[n];
            rowptr[nbase + n] = base + pre;
            cnts[nbase + n] = c;
            dis[nbase + n] = rsqrtf((float)c + 1.0f);
        }
    }
    __syncthreads();
    for (int i = tid; i < m; i += 256) {
        uint pk = bp[i];
        int ld = pk & 511;
        int s = (int)(pk >> 9);
        int r = atomicAdd(&lcur[ld], 1);
        csr[base + r] = s;
    }
    // prep_x for this bucket's nodes: xp[n][c] = dis[n]*x[n][c] (c<7), 0 (c==7)
    for (int i = tid; i < (nnum << 3); i += 256) {
        int n = i >> 3, c = i & 7;
        float dv = rsqrtf((float)lcnt[n] + 1.0f);
        xp[(((size_t)(nbase + n)) << 3) + c] =
            (c < INC) ? dv * x[(size_t)(nbase + n) * INC + c] : 0.0f;
    }
}

// ---------------- K4: gather8 -> gemm8 -> gemm_hid (all per-node), hwp bf16 out ----

__global__ __launch_bounds__(256) void k_l01(const float* __restrict__ xp,
                                             const int* __restrict__ csr,
                                             const int* __restrict__ rowptr,
                                             const int* __restrict__ cnts,
                                             const float* __restrict__ dis,
                                             const float* __restrict__ W0,
                                             const float* __restrict__ b0,
                                             const float* __restrict__ W1,
                                             ushort* __restrict__ hwpb) {
    __shared__ float sW0[INC][HID];       // 1.8 KB
    __shared__ float sW1[HID][HID];       // 16 KB
    __shared__ float sx[64][8];           // 2 KB
    __shared__ float h0T[HID][HID + 4];   // 17.4 KB  [k][n]
    __shared__ float sdis[64];
    __shared__ float sb0[HID];
    int tid = threadIdx.x;
    int n0 = blockIdx.x * 64;

    for (int i = tid; i < INC * HID; i += 256) sW0[i >> 6][i & 63] = W0[i];
    for (int i = tid; i < HID * HID; i += 256) sW1[i >> 6][i & 63] = W1[i];
    if (tid < 64) {
        sb0[tid] = b0[tid];
        sdis[tid] = (n0 + tid < NN) ? dis[n0 + tid] : 0.0f;
    }
    // --- gather8: 4 lanes x float2 per dst ---
    {
        int dl = tid >> 2, l = tid & 3;
        int d = n0 + dl;
        float2 a0 = {0.f, 0.f}, a1 = {0.f, 0.f};
        if (d < NN) {
            int beg = rowptr[d], num = cnts[d];
            a0 = ((const float2*)&xp[(size_t)d * 8])[l];
            int j = 0;
            while (j < num) {
                int chunk = min(num - j, 4);
                int iv = (l < chunk) ? csr[beg + j + l] : 0;
                int k = 0;
                for (; k + 2 <= chunk; k += 2) {
                    int s0 = __shfl(iv, k, 4);
                    int s1 = __shfl(iv, k + 1, 4);
                    float2 r0 = ((const float2*)&xp[(size_t)s0 * 8])[l];
                    float2 r1 = ((const float2*)&xp[(size_t)s1 * 8])[l];
                    a0.x += r0.x; a0.y += r0.y;
                    a1.x += r1.x; a1.y += r1.y;
                }
                for (; k < chunk; ++k) {
                    int s = __shfl(iv, k, 4);
                    float2 r = ((const float2*)&xp[(size_t)s * 8])[l];
                    a0.x += r.x; a0.y += r.y;
                }
                j += chunk;
            }
        }
        float dd = (tid >> 2) < 64 ? 0.0f : 0.0f;
        (void)dd;
        float ds = ((n0 + (tid >> 2)) < NN) ? dis[n0 + (tid >> 2)] : 0.0f;
        sx[dl][l * 2]     = ds * (a0.x + a1.x);
        sx[dl][l * 2 + 1] = ds * (a0.y + a1.y);
    }
    __syncthreads();
    // --- gemm8 -> h0T (relu, transposed into LDS) ---
    {
        int tn = tid >> 4, tc = tid & 15;
        float acc[4][4] = {};
#pragma unroll
        for (int k = 0; k < INC; ++k) {
            float hv[4];
#pragma unroll
            for (int i = 0; i < 4; ++i) hv[i] = sx[tn * 4 + i][k];
            float4 w4 = *(const float4*)&sW0[k][tc * 4];
            float wv[4] = {w4.x, w4.y, w4.z, w4.w};
#pragma unroll
            for (int i = 0; i < 4; ++i)
#pragma unroll
                for (int j = 0; j < 4; ++j)
                    acc[i][j] = fmaf(hv[i], wv[j], acc[i][j]);
        }
#pragma unroll
        for (int i = 0; i < 4; ++i)
#pragma unroll
            for (int j = 0; j < 4; ++j)
                h0T[tc * 4 + j][tn * 4 + i] = fmaxf(acc[i][j] + sb0[tc * 4 + j], 0.0f);
    }
    __syncthreads();
    // --- gemm_hid: 4x4 reg block, epilogue *dis -> bf16 pack -> store ---
    {
        int tn = tid >> 4, tc = tid & 15;
        float acc[4][4] = {};
#pragma unroll 8
        for (int k = 0; k < HID; ++k) {
            float4 h4 = *(const float4*)&h0T[k][tn * 4];
            float4 w4 = *(const float4*)&sW1[k][tc * 4];
            float hv[4] = {h4.x, h4.y, h4.z, h4.w};
            float wv[4] = {w4.x, w4.y, w4.z, w4.w};
#pragma unroll
            for (int i = 0; i < 4; ++i)
#pragma unroll
                for (int j = 0; j < 4; ++j)
                    acc[i][j] = fmaf(hv[i], wv[j], acc[i][j]);
        }
#pragma unroll
        for (int i = 0; i < 4; ++i) {
            int gn = n0 + tn * 4 + i;
            if (gn < NN) {
                float dsc = sdis[tn * 4 + i];
                uint2 o;
                o.x = pk2bf(dsc * acc[i][0], dsc * acc[i][1]);
                o.y = pk2bf(dsc * acc[i][2], dsc * acc[i][3]);
                ((uint2*)(hwpb + (size_t)gn * 64))[tc] = o;
            }
        }
    }
}

// ---------------- K5: gather64(bf16) -> [Wc=W2@linW] -> gemm_z, z bf16 out ----------

__global__ __launch_bounds__(512) void k_l2(const ushort* __restrict__ hwpb,
                                            const int* __restrict__ csr,
                                            const int* __restrict__ rowptr,
                                            const int* __restrict__ cnts,
                                            const float* __restrict__ dis,
                                            const float* __restrict__ b1,
                                            const float* __restrict__ W2,
                                            const float* __restrict__ linW,
                                            ushort* __restrict__ zb) {
    __shared__ float sWc[HID][16];        // 4 KB
    __shared__ float h1T[HID][HID + 4];   // 17.4 KB
    __shared__ float sdis[64];
    __shared__ float sb1[HID];
    int tid = threadIdx.x;
    int n0 = blockIdx.x * 64;

    // Wc = W2 @ linW (redundant per block; L2-served reads)
    for (int i = tid; i < HID * 16; i += 512) {
        int k = i >> 4, o = i & 15;
        float acc = 0.0f;
        if (o < OUTC)
            for (int q = 0; q < HID; ++q) acc += W2[k * HID + q] * linW[q * OUTC + o];
        sWc[k][o] = acc;
    }
    if (tid < 64) {
        sb1[tid] = b1[tid];
        sdis[tid] = (n0 + tid < NN) ? dis[n0 + tid] : 0.0f;
    }
    // --- gather64 bf16: 8 lanes x 16B (8 ch) per dst; relu epilogue -> h1T LDS ---
    {
        int dl = tid >> 3, l = tid & 7;
        int d = n0 + dl;
        float a0[8] = {}, a1[8] = {};
        if (d < NN) {
            int beg = rowptr[d], num = cnts[d];
            acc8(a0, ((const uint4*)(hwpb + (size_t)d * 64))[l]);  // self term
            int j = 0;
            while (j < num) {
                int chunk = min(num - j, 8);
                int iv = (l < chunk) ? csr[beg + j + l] : 0;
                int k = 0;
                for (; k + 2 <= chunk; k += 2) {
                    int s0 = __shfl(iv, k, 8);
                    int s1 = __shfl(iv, k + 1, 8);
                    uint4 r0 = ((const uint4*)(hwpb + (size_t)s0 * 64))[l];
                    uint4 r1 = ((const uint4*)(hwpb + (size_t)s1 * 64))[l];
                    acc8(a0, r0);
                    acc8(a1, r1);
                }
                if (k < chunk) {
                    int s = __shfl(iv, k, 8);
                    acc8(a0, ((const uint4*)(hwpb + (size_t)s * 64))[l]);
                }
                j += chunk;
            }
            float dd = sdis[dl];
#pragma unroll
            for (int i = 0; i < 8; ++i) {
                float v = fmaxf(dd * (a0[i] + a1[i]) + sb1[l * 8 + i], 0.0f);
                h1T[l * 8 + i][dl] = v;
            }
        } else {
#pragma unroll
            for (int i = 0; i < 8; ++i) h1T[l * 8 + i][dl] = 0.0f;
        }
    }
    __syncthreads();
    // --- gemm_z on first 256 threads: acc[4] per thread; z bf16 ---
    if (tid < 256) {
        int nq = tid >> 4, c = tid & 15;
        float acc[4] = {};
#pragma unroll 8
        for (int k = 0; k < HID; ++k) {
            float4 h4 = *(const float4*)&h1T[k][nq * 4];
            float w = sWc[k][c];
            acc[0] = fmaf(h4.x, w, acc[0]);
            acc[1] = fmaf(h4.y, w, acc[1]);
            acc[2] = fmaf(h4.z, w, acc[2]);
            acc[3] = fmaf(h4.w, w, acc[3]);
        }
#pragma unroll
        for (int i = 0; i < 4; ++i) {
            int gn = n0 + nq * 4 + i;
            if (gn < NN) zb[(size_t)gn * 16 + c] = f2bf(sdis[nq * 4 + i] * acc[i]);
        }
    }
}

// ---------------- K6: gather16(bf16) + mean-pool accumulate ----------------

__global__ __launch_bounds__(256) void k_l3pool(const ushort* __restrict__ zb,
                                                const int* __restrict__ csr,
                                                const int* __restrict__ rowptr,
                                                const int* __restrict__ cnts,
                                                const float* __restrict__ dis,
                                                const int* __restrict__ batch,
                                                float* __restrict__ sums,
                                                float* __restrict__ cnt) {
    __shared__ float lsum[16][16];  // 16 graph slots x 16 ch
    __shared__ int lcnt_[16];
    __shared__ int s_gmin;
    int tid = threadIdx.x;
    int n0 = blockIdx.x * 64;
    if (tid < 256) lsum[tid >> 4][tid & 15] = 0.0f;
    if (tid < 16) lcnt_[tid] = 0;
    if (tid == 0) s_gmin = batch[n0];
    __syncthreads();

    int dl = tid >> 2, l = tid & 3;
    int d = n0 + dl;
    if (d < NN) {
        int beg = rowptr[d], num = cnts[d];
        float4 a0 = cvt4(((const uint2*)(zb + (size_t)d * 16))[l]);
        float4 a1 = {0.f, 0.f, 0.f, 0.f};
        int j = 0;
        while (j < num) {
            int chunk = min(num - j, 4);
            int iv = (l < chunk) ? csr[beg + j + l] : 0;
            int k = 0;
            for (; k + 2 <= chunk; k += 2) {
                int s0 = __shfl(iv, k, 4);
                int s1 = __shfl(iv, k + 1, 4);
                float4 r0 = cvt4(((const uint2*)(zb + (size_t)s0 * 16))[l]);
                float4 r1 = cvt4(((const uint2*)(zb + (size_t)s1 * 16))[l]);
                a0.x += r0.x; a0.y += r0.y; a0.z += r0.z; a0.w += r0.w;
                a1.x += r1.x; a1.y += r1.y; a1.z += r1.z; a1.w += r1.w;
            }
            for (; k < chunk; ++k) {
                int s = __shfl(iv, k, 4);
                float4 r = cvt4(((const uint2*)(zb + (size_t)s * 16))[l]);
                a0.x += r.x; a0.y += r.y; a0.z += r.z; a0.w += r.w;
            }
            j += chunk;
        }
        float dd = dis[d];
        float4 v = {dd * (a0.x + a1.x), dd * (a0.y + a1.y),
                    dd * (a0.z + a1.z), dd * (a0.w + a1.w)};
        int g = batch[d];
        int slot = g - s_gmin;
        if (slot >= 0 && slot < 16) {
            atomicAdd(&lsum[slot][l * 4 + 0], v.x);
            atomicAdd(&lsum[slot][l * 4 + 1], v.y);
            atomicAdd(&lsum[slot][l * 4 + 2], v.z);
            atomicAdd(&lsum[slot][l * 4 + 3], v.w);
            if (l == 0) atomicAdd(&lcnt_[slot], 1);
        } else {  // pathological fallback (many graphs in one 64-node block)
            atomicAdd(&sums[g * 16 + l * 4 + 0], v.x);
            atomicAdd(&sums[g * 16 + l * 4 + 1], v.y);
            atomicAdd(&sums[g * 16 + l * 4 + 2], v.z);
            atomicAdd(&sums[g * 16 + l * 4 + 3], v.w);
            if (l == 0) atomicAdd(&cnt[g], 1.0f);
        }
    }
    __syncthreads();
    // flush nonzero slots
    {
        int slot = tid >> 4, c = tid & 15;
        if (lcnt_[slot] > 0) {
            atomicAdd(&sums[(s_gmin + slot) * 16 + c], lsum[slot][c]);
            if (c == 0) atomicAdd(&cnt[s_gmin + slot], (float)lcnt_[slot]);
        }
    }
}

// ---------------- K7: head (bc inline) ----------------

__global__ void k_final2(const float* __restrict__ sums, const float* __restrict__ cnt,
                         const float* __restrict__ b2, const float* __restrict__ linW,
                         const float* __restrict__ linb, float* __restrict__ out) {
    int t = blockIdx.x * blockDim.x + threadIdx.x;
    if (t < NG * OUTC) {
        int g = t / OUTC, o = t % OUTC;
        float bc = linb[o];
        for (int q = 0; q < HID; ++q) bc += b2[q] * linW[q * OUTC + o];
        out[t] = sums[g * 16 + o] / fmaxf(cnt[g], 1.0f) + bc;
    }
}

// ---------------- launch ----------------

extern "C" void kernel_launch(void* const* d_in, const int* in_sizes, int n_in,
                              void* d_out, int out_size, void* d_ws, size_t ws_size,
                              hipStream_t stream) {
    const float* x     = (const float*)d_in[0];
    const int*   ei    = (const int*)d_in[1];  // [2, NE]
    const int*   src   = ei;
    const int*   dst   = ei + NE;
    const int*   batch = (const int*)d_in[2];
    const float* W0 = (const float*)d_in[3];
    const float* b0 = (const float*)d_in[4];
    const float* W1 = (const float*)d_in[5];
    const float* b1 = (const float*)d_in[6];
    const float* W2 = (const float*)d_in[7];
    const float* b2 = (const float*)d_in[8];
    const float* linW = (const float*)d_in[9];
    const float* linb = (const float*)d_in[10];
    float* out = (float*)d_out;

    char* ws = (char*)d_ws;
    float*  xp     = (float*)ws;    ws += sizeof(float) * NN * 8;
    ushort* hwpb   = (ushort*)ws;   ws += sizeof(ushort) * NN * HID;
    ushort* zb     = (ushort*)ws;   ws += sizeof(ushort) * NN * 16;
    float*  dis    = (float*)ws;    ws += sizeof(float) * NN;
    float*  sums   = (float*)ws;    ws += sizeof(float) * NG * 16;
    float*  cnt    = (float*)ws;    ws += sizeof(float) * NG;
    int*    cnts   = (int*)ws;      ws += sizeof(int) * NN;
    int*    rowptr = (int*)ws;      ws += sizeof(int) * NN;
    int*    bktcur = (int*)ws;      ws += sizeof(int) * NBKT;
    uint*   binned = (uint*)ws;     ws += sizeof(uint) * NBKT * BCAP;
    int*    csr    = (int*)ws;      ws += sizeof(int) * NE;

    const int TB = 256;

    // CSR + normalization build
    k_zero<<<16, TB, 0, stream>>>(sums, cnt, bktcur);
    k_bin<<<NBIN_BLK, TB, 0, stream>>>(src, dst, bktcur, binned);
    k_build<<<NBKT, TB, 0, stream>>>(binned, bktcur, csr, rowptr, cnts, dis, x, xp);

    // layer 0+1 per-node chain (gather8 -> gemm8 -> gemm_hid), bf16 out
    k_l01<<<NBLK64, TB, 0, stream>>>(xp, csr, rowptr, cnts, dis, W0, b0, W1, hwpb);

    // layer 1 gather + layer 2 transform (folded head weights), bf16 out
    k_l2<<<NBLK64, 512, 0, stream>>>(hwpb, csr, rowptr, cnts, dis, b1, W2, linW, zb);

    // layer 2 gather + mean-pool accumulate
    k_l3pool<<<NBLK64, TB, 0, stream>>>(zb, csr, rowptr, cnts, dis, batch, sums, cnt);

    // head
    k_final2<<<(NG * OUTC + TB - 1) / TB, TB, 0, stream>>>(sums, cnt, b2, linW, linb, out);
}

// Round 10
// 220.721 us; speedup vs baseline: 5.1015x; 1.0168x over previous
//
#include <hip/hip_runtime.h>

#define NN 100000
#define NE 1200000
#define NG 256
#define INC 7
#define HID 64
#define OUTC 10

#define NBKT 196          // ceil(NN / 512) buckets of 512 nodes
#define BCAP 8192         // per-bucket binned capacity (avg 6144, max ~6500)
#define CSRCAP 10240      // per-bucket padded-CSR capacity (max ~8600)
#define BIN_CHUNK 4096    // edges per k_bin block (256 thr)
#define NBIN_BLK ((NE + BIN_CHUNK - 1) / BIN_CHUNK)  // 293
#define EPT (BIN_CHUNK / 256)  // 16 edges per thread
#define NBLK64 ((NN + 63) / 64)  // 1563

typedef unsigned int uint;
typedef unsigned short ushort;

// ---- bf16 helpers (RNE) ----
__device__ inline uint pk2bf(float a, float b) {
    uint ua = __float_as_uint(a);
    ua = (ua + 0x7fffu + ((ua >> 16) & 1u)) >> 16;
    uint ub = __float_as_uint(b);
    ub = (ub + 0x7fffu + ((ub >> 16) & 1u)) & 0xffff0000u;
    return ua | ub;
}
__device__ inline ushort f2bf(float f) {
    uint u = __float_as_uint(f);
    return (ushort)((u + 0x7fffu + ((u >> 16) & 1u)) >> 16);
}
__device__ inline void acc8(float* a, uint4 r) {
    a[0] += __uint_as_float(r.x << 16); a[1] += __uint_as_float(r.x & 0xffff0000u);
    a[2] += __uint_as_float(r.y << 16); a[3] += __uint_as_float(r.y & 0xffff0000u);
    a[4] += __uint_as_float(r.z << 16); a[5] += __uint_as_float(r.z & 0xffff0000u);
    a[6] += __uint_as_float(r.w << 16); a[7] += __uint_as_float(r.w & 0xffff0000u);
}
__device__ inline void acc4(float4& a, uint2 r) {
    a.x += __uint_as_float(r.x << 16); a.y += __uint_as_float(r.x & 0xffff0000u);
    a.z += __uint_as_float(r.y << 16); a.w += __uint_as_float(r.y & 0xffff0000u);
}

// ---------------- K1: zero init + Wc precompute ----------------

__global__ void k_zero(float* __restrict__ sums, float* __restrict__ cnt,
                       int* __restrict__ bktcur, float* __restrict__ xp,
                       ushort* __restrict__ hwpb, ushort* __restrict__ zb,
                       const float* __restrict__ W2, const float* __restrict__ linW,
                       float* __restrict__ wsWc) {
    int i = blockIdx.x * blockDim.x + threadIdx.x;
    if (i < NG * 16) sums[i] = 0.0f;
    if (i < NG) cnt[i] = 0.0f;
    if (i < NBKT) bktcur[i] = 0;
    if (i < 8) xp[(size_t)NN * 8 + i] = 0.0f;     // zero row (pad target)
    if (i < 64) hwpb[(size_t)NN * 64 + i] = 0;
    if (i < 16) zb[(size_t)NN * 16 + i] = 0;
    if (i < HID * 16) {                            // Wc = W2 @ linW (once)
        int k = i >> 4, o = i & 15;
        float acc = 0.0f;
        if (o < OUTC)
            for (int q = 0; q < HID; ++q) acc += W2[k * HID + q] * linW[q * OUTC + o];
        wsWc[i] = acc;
    }
}

// ---------------- K2: bin edges by dst>>9, packed (src<<9)|(dst&511) ----------------

__global__ __launch_bounds__(256) void k_bin(const int* __restrict__ src,
                                             const int* __restrict__ dst,
                                             int* __restrict__ bktcur,
                                             uint* __restrict__ binned) {
    __shared__ int hcnt[NBKT];
    __shared__ int hbase[NBKT];
    int tid = threadIdx.x;
    int e0 = blockIdx.x * BIN_CHUNK;
    int lim = NE - e0; if (lim > BIN_CHUNK) lim = BIN_CHUNK;

    int dr[EPT], sr[EPT];
    for (int b = tid; b < NBKT; b += 256) hcnt[b] = 0;
    __syncthreads();
#pragma unroll
    for (int u = 0; u < EPT; ++u) {
        int i = tid + u * 256;
        bool ok = i < lim;
        dr[u] = ok ? dst[e0 + i] : -1;
        sr[u] = ok ? src[e0 + i] : 0;
        if (ok) atomicAdd(&hcnt[dr[u] >> 9], 1);
    }
    __syncthreads();
    for (int b = tid; b < NBKT; b += 256) {
        int c = hcnt[b];
        hbase[b] = c ? atomicAdd(&bktcur[b], c) : 0;
        hcnt[b] = 0;  // reuse as intra-block rank counter
    }
    __syncthreads();
#pragma unroll
    for (int u = 0; u < EPT; ++u) {
        if (dr[u] >= 0) {
            int b = dr[u] >> 9;
            int r = atomicAdd(&hcnt[b], 1);
            binned[(size_t)b * BCAP + hbase[b] + r] = ((uint)sr[u] << 9) | (dr[u] & 511);
        }
    }
}

// ---------------- K3: per-bucket padded CSR + cnts + rowptr + dis + prep_x --------

__global__ __launch_bounds__(256) void k_build(const uint* __restrict__ binned,
                                               const int* __restrict__ bktcur,
                                               int* __restrict__ csr,
                                               int* __restrict__ rowptr,
                                               int* __restrict__ cnts,
                                               float* __restrict__ dis,
                                               const float* __restrict__ x,
                                               float* __restrict__ xp) {
    __shared__ int lcnt[512];
    __shared__ int lcur[512];
    __shared__ int sa[512], sb[512];
    int b = blockIdx.x;
    int tid = threadIdx.x;  // 256 threads
    int nbase = b << 9;
    int nnum = NN - nbase; if (nnum > 512) nnum = 512;
    int m = bktcur[b];
    const uint* bp = binned + (size_t)b * BCAP;
    int csrbase = b * CSRCAP;

    for (int n = tid; n < 512; n += 256) lcnt[n] = 0;
    __syncthreads();
    for (int i = tid; i < m; i += 256) atomicAdd(&lcnt[bp[i] & 511], 1);
    __syncthreads();
    // scan of PADDED counts
    for (int n = tid; n < 512; n += 256) sa[n] = (lcnt[n] + 7) & ~7;
    __syncthreads();
    int* p = sa; int* q = sb;
    for (int off = 1; off < 512; off <<= 1) {
        for (int n = tid; n < 512; n += 256)
            q[n] = p[n] + ((n >= off) ? p[n - off] : 0);
        __syncthreads();
        int* t2 = p; p = q; q = t2;
    }
    for (int n = tid; n < 512; n += 256) {
        int c = lcnt[n];
        int pad = (c + 7) & ~7;
        int pre = p[n] - pad;
        lcur[n] = pre;
        if (n < nnum) {
            rowptr[nbase + n] = csrbase + pre;
            cnts[nbase + n] = c;
            dis[nbase + n] = rsqrtf((float)c + 1.0f);
        }
    }
    __syncthreads();
    // scatter srcs
    for (int i = tid; i < m; i += 256) {
        uint pk = bp[i];
        int ld = pk & 511;
        int s = (int)(pk >> 9);
        int r = atomicAdd(&lcur[ld], 1);
        csr[csrbase + r] = s;
    }
    __syncthreads();
    // pad-fill with NN (zero feature row)
    for (int n = tid; n < 512; n += 256) {
        int c = lcnt[n];
        int endp = (lcur[n] - c) + ((c + 7) & ~7);
        for (int k = lcur[n]; k < endp; ++k) csr[csrbase + k] = NN;
    }
    // prep_x: xp[n][c] = dis[n]*x[n][c] (c<7), 0 (c==7)
    for (int i = tid; i < (nnum << 3); i += 256) {
        int n = i >> 3, c = i & 7;
        float dv = rsqrtf((float)lcnt[n] + 1.0f);
        xp[(((size_t)(nbase + n)) << 3) + c] =
            (c < INC) ? dv * x[(size_t)(nbase + n) * INC + c] : 0.0f;
    }
}

// ---------------- K4: gather8 -> gemm8 -> gemm_hid, hwp bf16 out ----------------

__global__ __launch_bounds__(256) void k_l01(const float* __restrict__ xp,
                                             const int* __restrict__ csr,
                                             const int* __restrict__ rowptr,
                                             const int* __restrict__ cnts,
                                             const float* __restrict__ dis,
                                             const float* __restrict__ W0,
                                             const float* __restrict__ b0,
                                             const float* __restrict__ W1,
                                             ushort* __restrict__ hwpb) {
    __shared__ float sW0[INC][HID];
    __shared__ float sW1[HID][HID];
    __shared__ float sx[64][8];
    __shared__ float h0T[HID][HID + 4];
    __shared__ float sdis[64];
    __shared__ float sb0[HID];
    int tid = threadIdx.x;
    int n0 = blockIdx.x * 64;

    for (int i = tid; i < INC * HID; i += 256) sW0[i >> 6][i & 63] = W0[i];
    for (int i = tid; i < HID * HID; i += 256) sW1[i >> 6][i & 63] = W1[i];
    if (tid < 64) {
        sb0[tid] = b0[tid];
        sdis[tid] = (n0 + tid < NN) ? dis[n0 + tid] : 0.0f;
    }
    // --- gather8: 4 lanes x float2 per dst; padded 8-deep ---
    {
        int dl = tid >> 2, l = tid & 3;
        int d = n0 + dl;
        float2 a0 = {0.f, 0.f}, a1 = {0.f, 0.f}, a2 = {0.f, 0.f}, a3 = {0.f, 0.f};
        float ds = 0.0f;
        if (d < NN) {
            int beg = rowptr[d];
            int npad = (cnts[d] + 7) & ~7;
            a0 = ((const float2*)&xp[(size_t)d * 8])[l];
            for (int j = 0; j < npad; j += 8) {
                int iv0 = csr[beg + j + l];
                int iv1 = csr[beg + j + 4 + l];
                int s0 = __shfl(iv0, 0, 4), s1 = __shfl(iv0, 1, 4);
                int s2 = __shfl(iv0, 2, 4), s3 = __shfl(iv0, 3, 4);
                int s4 = __shfl(iv1, 0, 4), s5 = __shfl(iv1, 1, 4);
                int s6 = __shfl(iv1, 2, 4), s7 = __shfl(iv1, 3, 4);
                float2 r0 = ((const float2*)&xp[(size_t)s0 * 8])[l];
                float2 r1 = ((const float2*)&xp[(size_t)s1 * 8])[l];
                float2 r2 = ((const float2*)&xp[(size_t)s2 * 8])[l];
                float2 r3 = ((const float2*)&xp[(size_t)s3 * 8])[l];
                float2 r4 = ((const float2*)&xp[(size_t)s4 * 8])[l];
                float2 r5 = ((const float2*)&xp[(size_t)s5 * 8])[l];
                float2 r6 = ((const float2*)&xp[(size_t)s6 * 8])[l];
                float2 r7 = ((const float2*)&xp[(size_t)s7 * 8])[l];
                a0.x += r0.x; a0.y += r0.y;  a1.x += r1.x; a1.y += r1.y;
                a2.x += r2.x; a2.y += r2.y;  a3.x += r3.x; a3.y += r3.y;
                a0.x += r4.x; a0.y += r4.y;  a1.x += r5.x; a1.y += r5.y;
                a2.x += r6.x; a2.y += r6.y;  a3.x += r7.x; a3.y += r7.y;
            }
            ds = dis[d];
        }
        sx[dl][l * 2]     = ds * ((a0.x + a1.x) + (a2.x + a3.x));
        sx[dl][l * 2 + 1] = ds * ((a0.y + a1.y) + (a2.y + a3.y));
    }
    __syncthreads();
    // --- gemm8 -> h0T (relu, transposed into LDS) ---
    {
        int tn = tid >> 4, tc = tid & 15;
        float acc[4][4] = {};
#pragma unroll
        for (int k = 0; k < INC; ++k) {
            float hv[4];
#pragma unroll
            for (int i = 0; i < 4; ++i) hv[i] = sx[tn * 4 + i][k];
            float4 w4 = *(const float4*)&sW0[k][tc * 4];
            float wv[4] = {w4.x, w4.y, w4.z, w4.w};
#pragma unroll
            for (int i = 0; i < 4; ++i)
#pragma unroll
                for (int j = 0; j < 4; ++j)
                    acc[i][j] = fmaf(hv[i], wv[j], acc[i][j]);
        }
#pragma unroll
        for (int i = 0; i < 4; ++i)
#pragma unroll
            for (int j = 0; j < 4; ++j)
                h0T[tc * 4 + j][tn * 4 + i] = fmaxf(acc[i][j] + sb0[tc * 4 + j], 0.0f);
    }
    __syncthreads();
    // --- gemm_hid: 4x4 reg block, epilogue *dis -> bf16 pack -> store ---
    {
        int tn = tid >> 4, tc = tid & 15;
        float acc[4][4] = {};
#pragma unroll 8
        for (int k = 0; k < HID; ++k) {
            float4 h4 = *(const float4*)&h0T[k][tn * 4];
            float4 w4 = *(const float4*)&sW1[k][tc * 4];
            float hv[4] = {h4.x, h4.y, h4.z, h4.w};
            float wv[4] = {w4.x, w4.y, w4.z, w4.w};
#pragma unroll
            for (int i = 0; i < 4; ++i)
#pragma unroll
                for (int j = 0; j < 4; ++j)
                    acc[i][j] = fmaf(hv[i], wv[j], acc[i][j]);
        }
#pragma unroll
        for (int i = 0; i < 4; ++i) {
            int gn = n0 + tn * 4 + i;
            if (gn < NN) {
                float dsc = sdis[tn * 4 + i];
                uint2 o;
                o.x = pk2bf(dsc * acc[i][0], dsc * acc[i][1]);
                o.y = pk2bf(dsc * acc[i][2], dsc * acc[i][3]);
                ((uint2*)(hwpb + (size_t)gn * 64))[tc] = o;
            }
        }
    }
}

// ---------------- K5: gather64(bf16, 8-deep) -> gemm_z, z bf16 out ----------------

__global__ __launch_bounds__(512) void k_l2(const ushort* __restrict__ hwpb,
                                            const int* __restrict__ csr,
                                            const int* __restrict__ rowptr,
                                            const int* __restrict__ cnts,
                                            const float* __restrict__ dis,
                                            const float* __restrict__ b1,
                                            const float* __restrict__ wsWc,
                                            ushort* __restrict__ zb) {
    __shared__ float sWc[HID][16];        // 4 KB
    __shared__ float h1T[HID][HID + 4];   // 17.4 KB
    __shared__ float sdis[64];
    __shared__ float sb1[HID];
    int tid = threadIdx.x;
    int n0 = blockIdx.x * 64;

    for (int i = tid; i < HID * 16; i += 512) sWc[i >> 4][i & 15] = wsWc[i];
    if (tid < 64) {
        sb1[tid] = b1[tid];
        sdis[tid] = (n0 + tid < NN) ? dis[n0 + tid] : 0.0f;
    }
    __syncthreads();
    // --- gather64: 8 lanes x uint4 (8 ch) per dst; padded 8-deep ---
    {
        int dl = tid >> 3, l = tid & 7;
        int d = n0 + dl;
        if (d < NN) {
            float a0[8] = {}, a1[8] = {};
            int beg = rowptr[d];
            int npad = (cnts[d] + 7) & ~7;
            acc8(a0, ((const uint4*)(hwpb + (size_t)d * 64))[l]);  // self term
            for (int j = 0; j < npad; j += 8) {
                int iv = csr[beg + j + l];
                int s0 = __shfl(iv, 0, 8), s1 = __shfl(iv, 1, 8);
                int s2 = __shfl(iv, 2, 8), s3 = __shfl(iv, 3, 8);
                int s4 = __shfl(iv, 4, 8), s5 = __shfl(iv, 5, 8);
                int s6 = __shfl(iv, 6, 8), s7 = __shfl(iv, 7, 8);
                uint4 r0 = ((const uint4*)(hwpb + (size_t)s0 * 64))[l];
                uint4 r1 = ((const uint4*)(hwpb + (size_t)s1 * 64))[l];
                uint4 r2 = ((const uint4*)(hwpb + (size_t)s2 * 64))[l];
                uint4 r3 = ((const uint4*)(hwpb + (size_t)s3 * 64))[l];
                uint4 r4 = ((const uint4*)(hwpb + (size_t)s4 * 64))[l];
                uint4 r5 = ((const uint4*)(hwpb + (size_t)s5 * 64))[l];
                uint4 r6 = ((const uint4*)(hwpb + (size_t)s6 * 64))[l];
                uint4 r7 = ((const uint4*)(hwpb + (size_t)s7 * 64))[l];
                acc8(a0, r0); acc8(a1, r1); acc8(a0, r2); acc8(a1, r3);
                acc8(a0, r4); acc8(a1, r5); acc8(a0, r6); acc8(a1, r7);
            }
            float dd = sdis[dl];
#pragma unroll
            for (int i = 0; i < 8; ++i) {
                h1T[l * 8 + i][dl] = fmaxf(dd * (a0[i] + a1[i]) + sb1[l * 8 + i], 0.0f);
            }
        } else {
#pragma unroll
            for (int i = 0; i < 8; ++i) h1T[l * 8 + i][dl] = 0.0f;
        }
    }
    __syncthreads();
    // --- gemm_z on first 256 threads: acc[4] per thread; z bf16 ---
    if (tid < 256) {
        int nq = tid >> 4, c = tid & 15;
        float acc[4] = {};
#pragma unroll 8
        for (int k = 0; k < HID; ++k) {
            float4 h4 = *(const float4*)&h1T[k][nq * 4];
            float w = sWc[k][c];
            acc[0] = fmaf(h4.x, w, acc[0]);
            acc[1] = fmaf(h4.y, w, acc[1]);
            acc[2] = fmaf(h4.z, w, acc[2]);
            acc[3] = fmaf(h4.w, w, acc[3]);
        }
#pragma unroll
        for (int i = 0; i < 4; ++i) {
            int gn = n0 + nq * 4 + i;
            if (gn < NN) zb[(size_t)gn * 16 + c] = f2bf(sdis[nq * 4 + i] * acc[i]);
        }
    }
}

// ---------------- K6: gather16(bf16, 8-deep) + mean-pool accumulate ----------------

__global__ __launch_bounds__(256) void k_l3pool(const ushort* __restrict__ zb,
                                                const int* __restrict__ csr,
                                                const int* __restrict__ rowptr,
                                                const int* __restrict__ cnts,
                                                const float* __restrict__ dis,
                                                const int* __restrict__ batch,
                                                float* __restrict__ sums,
                                                float* __restrict__ cnt) {
    __shared__ float lsum[16][16];
    __shared__ int lcnt_[16];
    __shared__ int s_gmin;
    int tid = threadIdx.x;
    int n0 = blockIdx.x * 64;
    if (tid < 256) lsum[tid >> 4][tid & 15] = 0.0f;
    if (tid < 16) lcnt_[tid] = 0;
    if (tid == 0) s_gmin = batch[n0];
    __syncthreads();

    int dl = tid >> 2, l = tid & 3;
    int d = n0 + dl;
    if (d < NN) {
        int beg = rowptr[d];
        int npad = (cnts[d] + 7) & ~7;
        float4 a0 = {0.f, 0.f, 0.f, 0.f}, a1 = {0.f, 0.f, 0.f, 0.f};
        float4 a2 = {0.f, 0.f, 0.f, 0.f}, a3 = {0.f, 0.f, 0.f, 0.f};
        acc4(a0, ((const uint2*)(zb + (size_t)d * 16))[l]);  // self term
        for (int j = 0; j < npad; j += 8) {
            int iv0 = csr[beg + j + l];
            int iv1 = csr[beg + j + 4 + l];
            int s0 = __shfl(iv0, 0, 4), s1 = __shfl(iv0, 1, 4);
            int s2 = __shfl(iv0, 2, 4), s3 = __shfl(iv0, 3, 4);
            int s4 = __shfl(iv1, 0, 4), s5 = __shfl(iv1, 1, 4);
            int s6 = __shfl(iv1, 2, 4), s7 = __shfl(iv1, 3, 4);
            uint2 r0 = ((const uint2*)(zb + (size_t)s0 * 16))[l];
            uint2 r1 = ((const uint2*)(zb + (size_t)s1 * 16))[l];
            uint2 r2 = ((const uint2*)(zb + (size_t)s2 * 16))[l];
            uint2 r3 = ((const uint2*)(zb + (size_t)s3 * 16))[l];
            uint2 r4 = ((const uint2*)(zb + (size_t)s4 * 16))[l];
            uint2 r5 = ((const uint2*)(zb + (size_t)s5 * 16))[l];
            uint2 r6 = ((const uint2*)(zb + (size_t)s6 * 16))[l];
            uint2 r7 = ((const uint2*)(zb + (size_t)s7 * 16))[l];
            acc4(a0, r0); acc4(a1, r1); acc4(a2, r2); acc4(a3, r3);
            acc4(a0, r4); acc4(a1, r5); acc4(a2, r6); acc4(a3, r7);
        }
        float dd = dis[d];
        float4 v = {dd * ((a0.x + a1.x) + (a2.x + a3.x)),
                    dd * ((a0.y + a1.y) + (a2.y + a3.y)),
                    dd * ((a0.z + a1.z) + (a2.z + a3.z)),
                    dd * ((a0.w + a1.w) + (a2.w + a3.w))};
        int g = batch[d];
        int slot = g - s_gmin;
        if (slot >= 0 && slot < 16) {
            atomicAdd(&lsum[slot][l * 4 + 0], v.x);
            atomicAdd(&lsum[slot][l * 4 + 1], v.y);
            atomicAdd(&lsum[slot][l * 4 + 2], v.z);
            atomicAdd(&lsum[slot][l * 4 + 3], v.w);
            if (l == 0) atomicAdd(&lcnt_[slot], 1);
        } else {
            atomicAdd(&sums[g * 16 + l * 4 + 0], v.x);
            atomicAdd(&sums[g * 16 + l * 4 + 1], v.y);
            atomicAdd(&sums[g * 16 + l * 4 + 2], v.z);
            atomicAdd(&sums[g * 16 + l * 4 + 3], v.w);
            if (l == 0) atomicAdd(&cnt[g], 1.0f);
        }
    }
    __syncthreads();
    {
        int slot = tid >> 4, c = tid & 15;
        if (lcnt_[slot] > 0) {
            atomicAdd(&sums[(s_gmin + slot) * 16 + c], lsum[slot][c]);
            if (c == 0) atomicAdd(&cnt[s_gmin + slot], (float)lcnt_[slot]);
        }
    }
}

// ---------------- K7: head ----------------

__global__ void k_final2(const float* __restrict__ sums, const float* __restrict__ cnt,
                         const float* __restrict__ b2, const float* __restrict__ linW,
                         const float* __restrict__ linb, float* __restrict__ out) {
    int t = blockIdx.x * blockDim.x + threadIdx.x;
    if (t < NG * OUTC) {
        int g = t / OUTC, o = t % OUTC;
        float bc = linb[o];
        for (int q = 0; q < HID; ++q) bc += b2[q] * linW[q * OUTC + o];
        out[t] = sums[g * 16 + o] / fmaxf(cnt[g], 1.0f) + bc;
    }
}

// ---------------- launch ----------------

extern "C" void kernel_launch(void* const* d_in, const int* in_sizes, int n_in,
                              void* d_out, int out_size, void* d_ws, size_t ws_size,
                              hipStream_t stream) {
    const float* x     = (const float*)d_in[0];
    const int*   ei    = (const int*)d_in[1];  // [2, NE]
    const int*   src   = ei;
    const int*   dst   = ei + NE;
    const int*   batch = (const int*)d_in[2];
    const float* W0 = (const float*)d_in[3];
    const float* b0 = (const float*)d_in[4];
    const float* W1 = (const float*)d_in[5];
    const float* b1 = (const float*)d_in[6];
    const float* W2 = (const float*)d_in[7];
    const float* b2 = (const float*)d_in[8];
    const float* linW = (const float*)d_in[9];
    const float* linb = (const float*)d_in[10];
    float* out = (float*)d_out;

    char* ws = (char*)d_ws;
    float*  xp     = (float*)ws;    ws += sizeof(float) * (NN + 1) * 8;
    ushort* hwpb   = (ushort*)ws;   ws += sizeof(ushort) * (NN + 1) * HID;
    ushort* zb     = (ushort*)ws;   ws += sizeof(ushort) * (NN + 1) * 16;
    float*  dis    = (float*)ws;    ws += sizeof(float) * NN;
    float*  sums   = (float*)ws;    ws += sizeof(float) * NG * 16;
    float*  cnt    = (float*)ws;    ws += sizeof(float) * NG;
    float*  wsWc   = (float*)ws;    ws += sizeof(float) * HID * 16;
    int*    cnts   = (int*)ws;      ws += sizeof(int) * NN;
    int*    rowptr = (int*)ws;      ws += sizeof(int) * NN;
    int*    bktcur = (int*)ws;      ws += sizeof(int) * NBKT;
    uint*   binned = (uint*)ws;     ws += sizeof(uint) * NBKT * BCAP;
    int*    csr    = (int*)ws;      ws += sizeof(int) * NBKT * CSRCAP;

    const int TB = 256;

    // CSR + normalization build (padded counting sort, dense writes)
    k_zero<<<16, TB, 0, stream>>>(sums, cnt, bktcur, xp, hwpb, zb, W2, linW, wsWc);
    k_bin<<<NBIN_BLK, TB, 0, stream>>>(src, dst, bktcur, binned);
    k_build<<<NBKT, TB, 0, stream>>>(binned, bktcur, csr, rowptr, cnts, dis, x, xp);

    // layer 0+1 per-node chain (gather8 -> gemm8 -> gemm_hid), bf16 out
    k_l01<<<NBLK64, TB, 0, stream>>>(xp, csr, rowptr, cnts, dis, W0, b0, W1, hwpb);

    // layer 1 gather + layer 2 transform (folded head weights), bf16 out
    k_l2<<<NBLK64, 512, 0, stream>>>(hwpb, csr, rowptr, cnts, dis, b1, wsWc, zb);

    // layer 2 gather + mean-pool accumulate
    k_l3pool<<<NBLK64, TB, 0, stream>>>(zb, csr, rowptr, cnts, dis, batch, sums, cnt);

    // head
    k_final2<<<(NG * OUTC + TB - 1) / TB, TB, 0, stream>>>(sums, cnt, b2, linW, linb, out);
}